// Round 12
// baseline (272.506 us; speedup 1.0000x reference)
//
#include <hip/hip_runtime.h>

#define EPS_BN 1e-5f

typedef __bf16 bf16x8 __attribute__((ext_vector_type(8)));
typedef float f32x4 __attribute__((ext_vector_type(4)));

__device__ __forceinline__ unsigned short f2bf(float f) {
  union { float f; unsigned u; } v; v.f = f;
  unsigned r = v.u + 0x7fffu + ((v.u >> 16) & 1u);
  return (unsigned short)(r >> 16);
}
__device__ __forceinline__ float bf2f(unsigned short h) {
  union { unsigned u; float f; } v; v.u = ((unsigned)h) << 16;
  return v.f;
}

// ---------------- fused prep (act1P: pad-ring zeroing only; interior written by gemm1f) ----------------
__global__ __launch_bounds__(256) void prep_all(
    const float* __restrict__ w1, const float* __restrict__ w2, const float* __restrict__ woff,
    const float* __restrict__ w3,
    const float* g1, const float* b1, const float* m1, const float* v1,
    const float* g2, const float* b2, const float* m2, const float* v2, const float* bconv2,
    const float* g3, const float* b3, const float* m3, const float* v3,
    unsigned short* __restrict__ w1b, unsigned short* __restrict__ w2r,
    uint4* __restrict__ act1Pz, unsigned short* __restrict__ wob,
    unsigned short* __restrict__ w3b, float* __restrict__ shift3,
    float* s1, float* h1, float* s2, float* h2) {
  int bid = blockIdx.x, tid = threadIdx.x;
  if (bid < 1024) {
    int i = bid * 256 + tid;
    w1b[i] = f2bf(w1[i]);
  } else if (bid < 3328) {
    int i = (bid - 1024) * 256 + tid;
    int o = i / 2304, r = i % 2304;
    int kk = r / 256, c = r % 256;
    w2r[i] = f2bf(w2[(size_t)o * 2304 + c * 9 + kk]);
  } else if (bid < 3592) {
    // zero the 2-wide pad ring of act1P: 4 batches x 528 ring cells x 32 uint4
    int i = (bid - 3328) * 256 + tid;        // 0..67583
    int cell = i >> 5, q = i & 31;
    int b = cell / 528, r = cell - b * 528;
    int row, col;
    if (r < 136) { row = r / 68; col = r % 68; }
    else if (r < 272) { int rr = r - 136; row = 66 + rr / 68; col = rr % 68; }
    else { int rr = r - 272; row = 2 + (rr >> 2); int c4 = rr & 3; col = (c4 < 2) ? c4 : c4 + 64; }
    act1Pz[(((size_t)(b * 68) + row) * 68 + col) * 32 + q] = uint4{0, 0, 0, 0};
  } else if (bid < 3880) {
    int i = (bid - 3592) * 256 + tid;
    int o = i / 2304, r = i % 2304;
    int kk = r / 256, c = r % 256;
    wob[i] = (o < 18) ? f2bf(woff[(size_t)o * 2304 + c * 9 + kk]) : (unsigned short)0;
  } else if (bid < 4904) {
    int i = (bid - 3880) * 256 + tid;
    int o = i >> 8;
    float sc = rsqrtf(v3[o] + EPS_BN) * g3[o];
    w3b[i] = f2bf(w3[i] * sc);
  } else if (bid < 4908) {
    int c = (bid - 4904) * 256 + tid;
    float sc = rsqrtf(v3[c] + EPS_BN) * g3[c];
    shift3[c] = b3[c] - m3[c] * sc;
  } else {
    int c = tid;
    float sc1 = rsqrtf(v1[c] + EPS_BN) * g1[c];
    s1[c] = sc1; h1[c] = b1[c] - m1[c] * sc1;
    float sc2 = rsqrtf(v2[c] + EPS_BN) * g2[c];
    s2[c] = sc2; h2[c] = b2[c] + (bconv2[c] - m2[c]) * sc2;
  }
}

// ---------------- GEMM1: fused x-transpose, full K=1024, depth-2 A-regs + depth-2 B-LDS,
// fused BN1+ReLU epilogue -> act1T + padded act1P. Grid (2,128) = 1 blk/CU.
// Per body(t): issue A(t+2)->va[t&1] (16 loads), B(t+2)->sB[(t+2)&3] (2 DMAs);
// vmcnt(20) leaves {B(t+1),A(t+2),B(t+2)}=20, drains A(t+1)+B(t) (FIFO, A-before-B order).
__global__ __launch_bounds__(256) void gemm1f(
    const float* __restrict__ x, const unsigned short* __restrict__ Bm,
    const float* __restrict__ scale, const float* __restrict__ shift,
    unsigned short* __restrict__ outT, unsigned short* __restrict__ outP) {
  __shared__ __align__(16) char blob[16896];              // sA0(8K)|sB0(8K); tbuf aliases
  __shared__ __align__(16) unsigned short sA1[4096];
  __shared__ __align__(16) unsigned short sB1[4096];
  __shared__ __align__(16) unsigned short sB2[4096];
  __shared__ __align__(16) unsigned short sB3[4096];
  unsigned short* sA0 = (unsigned short*)blob;
  unsigned short* sB0 = (unsigned short*)(blob + 8192);
  float* tbuf = (float*)blob;                             // epilogue only
  int tid = threadIdx.x, lane = tid & 63, wv = tid >> 6;
  int m0 = blockIdx.y * 128, n0 = blockIdx.x * 128;
  f32x4 acc[4][4] = {};
  // B staging mapping (pre-swizzled source col)
  int rowB = tid >> 2;
  int kcolBs = (((tid & 3) ^ (rowB & 3))) * 8;
  // A staging mapping: 2 threads/row, 16 ch each; swizzled write slots
  int px = tid & 127, chalf = tid >> 7;
  int s0w = (chalf * 2) ^ (px & 3), s1w = (chalf * 2 + 1) ^ (px & 3);
  int bb = m0 >> 12, p0 = m0 & 4095;
  const float* xa = x + (size_t)bb * 4194304 + (size_t)(chalf * 16) * 4096 + (p0 + px);
  int wm = wv & 1, wn = wv >> 1;
  int lane15 = lane & 15, quad = lane >> 4, l3 = lane & 3;

  float va0[16], va1[16];

#define G1_ISSUE_A(VA, K0)                                                                \
  {                                                                                       \
    const float* xp = xa + (size_t)(K0) * 4096;                                           \
    _Pragma("unroll") for (int j = 0; j < 16; ++j) (VA)[j] = xp[(size_t)j * 4096];        \
  }

#define G1_ISSUE_B(DB, K0)                                                                \
  {                                                                                       \
    _Pragma("unroll") for (int r = 0; r < 2; ++r) {                                       \
      const unsigned short* gp = Bm + (size_t)(n0 + r * 64 + rowB) * 1024 + (K0) + kcolBs;\
      __builtin_amdgcn_global_load_lds((const __attribute__((address_space(1))) void*)gp, \
          (__attribute__((address_space(3))) void*)&(DB)[r * 2048 + wv * 512], 16, 0, 0); \
    }                                                                                     \
  }

#define G1_CVT_WRITE(VA, DA)                                                              \
  {                                                                                       \
    unsigned o8[8];                                                                       \
    _Pragma("unroll") for (int j = 0; j < 8; ++j)                                         \
      o8[j] = (unsigned)f2bf((VA)[2 * j]) | ((unsigned)f2bf((VA)[2 * j + 1]) << 16);      \
    *(uint4*)((DA) + px * 32 + s0w * 8) = uint4{o8[0], o8[1], o8[2], o8[3]};              \
    *(uint4*)((DA) + px * 32 + s1w * 8) = uint4{o8[4], o8[5], o8[6], o8[7]};              \
  }

#define G1_COMPUTE(DA, DB)                                                                \
  {                                                                                       \
    bf16x8 afr[4], bfr[4];                                                                \
    _Pragma("unroll") for (int mi = 0; mi < 4; ++mi)                                      \
      afr[mi] = *(const bf16x8*)&(DA)[(wm * 64 + mi * 16 + lane15) * 32 + (quad ^ l3) * 8]; \
    _Pragma("unroll") for (int ni = 0; ni < 4; ++ni)                                      \
      bfr[ni] = *(const bf16x8*)&(DB)[(wn * 64 + ni * 16 + lane15) * 32 + (quad ^ l3) * 8]; \
    _Pragma("unroll") for (int mi = 0; mi < 4; ++mi)                                      \
      _Pragma("unroll") for (int ni = 0; ni < 4; ++ni)                                    \
        acc[mi][ni] =                                                                     \
            __builtin_amdgcn_mfma_f32_16x16x32_bf16(afr[mi], bfr[ni], acc[mi][ni], 0, 0, 0); \
  }

// body(t): VAI = va[t&1] (receives A(t+2)); VAC = va[(t+1)&1] (holds A(t+1), cvt'd this body);
// AC = sA[t&1]; AW = sA[(t+1)&1]; BC = sB[t&3]; BI = sB[(t+2)&3].
#define G1F_BODY(VAI, VAC, AC, AW, BC, BI, K2)                                            \
  {                                                                                       \
    G1_ISSUE_A(VAI, K2);                                                                  \
    G1_ISSUE_B(BI, K2);                                                                   \
    asm volatile("s_waitcnt vmcnt(20)" ::: "memory");                                     \
    asm volatile("s_waitcnt lgkmcnt(0)" ::: "memory");                                    \
    __builtin_amdgcn_s_barrier();                                                         \
    G1_COMPUTE(AC, BC);                                                                   \
    G1_CVT_WRITE(VAC, AW);                                                                \
    __builtin_amdgcn_s_barrier();                                                         \
  }

  // prologue: A(0)->va0->sA0; B(0)->sB0; A(1)->va1; B(1)->sB1
  G1_ISSUE_A(va0, 0);
  G1_ISSUE_B(sB0, 0);
  asm volatile("s_waitcnt vmcnt(2)" ::: "memory");
  G1_CVT_WRITE(va0, sA0);
  G1_ISSUE_A(va1, 32);
  G1_ISSUE_B(sB1, 32);
  // bodies 0..27 (7 groups of 4), then 28, 29, then 2 tail bodies (nst = 32)
  for (int t = 0; t < 28; t += 4) {
    G1F_BODY(va0, va1, sA0, sA1, sB0, sB2, (t + 2) * 32);
    G1F_BODY(va1, va0, sA1, sA0, sB1, sB3, (t + 3) * 32);
    G1F_BODY(va0, va1, sA0, sA1, sB2, sB0, (t + 4) * 32);
    G1F_BODY(va1, va0, sA1, sA0, sB3, sB1, (t + 5) * 32);
  }
  G1F_BODY(va0, va1, sA0, sA1, sB0, sB2, 30 * 32);  // t=28
  G1F_BODY(va1, va0, sA1, sA0, sB1, sB3, 31 * 32);  // t=29
  // t=30: no issues; drain A(31), keep B(31)
  asm volatile("s_waitcnt vmcnt(2)" ::: "memory");
  asm volatile("s_waitcnt lgkmcnt(0)" ::: "memory");
  __builtin_amdgcn_s_barrier();
  G1_COMPUTE(sA0, sB2);
  G1_CVT_WRITE(va1, sA1);
  __builtin_amdgcn_s_barrier();
  // t=31: full drain
  asm volatile("s_waitcnt vmcnt(0)" ::: "memory");
  asm volatile("s_waitcnt lgkmcnt(0)" ::: "memory");
  __builtin_amdgcn_s_barrier();
  G1_COMPUTE(sA1, sB3);
#undef G1_ISSUE_A
#undef G1_ISSUE_B
#undef G1_CVT_WRITE
#undef G1_COMPUTE
#undef G1F_BODY

  // fused BN1+ReLU epilogue: LDS-transpose, write act1T + padded act1P
  int trow = tid >> 3;
  int tcol16 = (tid & 7) * 16;
  int c0e = n0 + tcol16;
  float sc[16], sh[16];
#pragma unroll
  for (int q = 0; q < 4; ++q) {
    *(float4*)&sc[q * 4] = *(const float4*)(scale + c0e + q * 4);
    *(float4*)&sh[q * 4] = *(const float4*)(shift + c0e + q * 4);
  }
  int growBase = m0 + (trow >> 4) * 64 + (trow & 15);
#pragma unroll
  for (int mi = 0; mi < 4; ++mi) {
    __syncthreads();
#pragma unroll
    for (int ni = 0; ni < 4; ++ni)
#pragma unroll
      for (int reg = 0; reg < 4; ++reg)
        tbuf[(wm * 16 + quad * 4 + reg) * 132 + wn * 64 + ni * 16 + lane15] = acc[mi][ni][reg];
    __syncthreads();
    int gr = growBase + mi * 16;
    const float* lp = &tbuf[trow * 132 + tcol16];
    unsigned o[8];
#pragma unroll
    for (int j = 0; j < 8; ++j) {
      float lo = fmaxf(lp[2 * j] * sc[2 * j] + sh[2 * j], 0.f);
      float hi = fmaxf(lp[2 * j + 1] * sc[2 * j + 1] + sh[2 * j + 1], 0.f);
      o[j] = (unsigned)f2bf(lo) | ((unsigned)f2bf(hi) << 16);
    }
    uint4 pk0{o[0], o[1], o[2], o[3]}, pk1{o[4], o[5], o[6], o[7]};
    unsigned short* op = outT + (size_t)gr * 256 + c0e;
    *(uint4*)(op) = pk0;
    *(uint4*)(op + 8) = pk1;
    int b2 = gr >> 12, p = gr & 4095;
    unsigned short* pp = outP + (((size_t)(b2 * 68) + (p >> 6) + 2) * 68 + (p & 63) + 2) * 256 + c0e;
    *(uint4*)(pp) = pk0;
    *(uint4*)(pp + 8) = pk1;
  }
}

// ---------------- GEMM2: full K=2304, BK=32 depth-2 (4 buffer sets), swizzled,
// fused bias+BN2+ReLU epilogue -> act2T. Grid (2,128) = 1 blk/CU.
// Stage = 4 DMAs; steady vmcnt(8) = 2 stages in flight; tail 8/4/0.
__global__ __launch_bounds__(256) void gemm2f(
    const unsigned short* __restrict__ A, const unsigned short* __restrict__ Bm,
    const float* __restrict__ scale, const float* __restrict__ shift,
    unsigned short* __restrict__ outT) {
  __shared__ __align__(16) char blob[16896];              // sA0(8K)|sB0(8K); tbuf aliases
  __shared__ __align__(16) unsigned short sA1[4096];
  __shared__ __align__(16) unsigned short sB1[4096];
  __shared__ __align__(16) unsigned short sA2[4096];
  __shared__ __align__(16) unsigned short sB2[4096];
  __shared__ __align__(16) unsigned short sA3[4096];
  __shared__ __align__(16) unsigned short sB3[4096];
  unsigned short* sA0 = (unsigned short*)blob;
  unsigned short* sB0 = (unsigned short*)(blob + 8192);
  float* tbuf = (float*)blob;                             // epilogue only
  int tid = threadIdx.x, lane = tid & 63, wv = tid >> 6;
  int m0 = blockIdx.y * 128, n0 = blockIdx.x * 128;
  f32x4 acc[4][4] = {};
  int rowA = tid >> 2;                         // 0..63
  int kcolS = (((tid & 3) ^ (rowA & 3))) * 8;  // pre-swizzled source col
  int wm = wv & 1, wn = wv >> 1;
  int lane15 = lane & 15, quad = lane >> 4, l3 = lane & 3;

#define GS_STAGE(dA, dB, K0)                                                              \
  {                                                                                       \
    int k0_ = (K0);                                                                       \
    _Pragma("unroll") for (int r = 0; r < 2; ++r) {                                       \
      const unsigned short* gp = A + (size_t)(m0 + r * 64 + rowA) * 2304 + k0_ + kcolS;   \
      __builtin_amdgcn_global_load_lds((const __attribute__((address_space(1))) void*)gp, \
          (__attribute__((address_space(3))) void*)&(dA)[r * 2048 + wv * 512], 16, 0, 0); \
    }                                                                                     \
    _Pragma("unroll") for (int r = 0; r < 2; ++r) {                                       \
      const unsigned short* gp = Bm + (size_t)(n0 + r * 64 + rowA) * 2304 + k0_ + kcolS;  \
      __builtin_amdgcn_global_load_lds((const __attribute__((address_space(1))) void*)gp, \
          (__attribute__((address_space(3))) void*)&(dB)[r * 2048 + wv * 512], 16, 0, 0); \
    }                                                                                     \
  }

#define GS_COMPUTE(dA, dB)                                                                \
  {                                                                                       \
    bf16x8 afr[4], bfr[4];                                                                \
    _Pragma("unroll") for (int mi = 0; mi < 4; ++mi)                                      \
      afr[mi] = *(const bf16x8*)&(dA)[(wm * 64 + mi * 16 + lane15) * 32 + (quad ^ l3) * 8]; \
    _Pragma("unroll") for (int ni = 0; ni < 4; ++ni)                                      \
      bfr[ni] = *(const bf16x8*)&(dB)[(wn * 64 + ni * 16 + lane15) * 32 + (quad ^ l3) * 8]; \
    _Pragma("unroll") for (int mi = 0; mi < 4; ++mi)                                      \
      _Pragma("unroll") for (int ni = 0; ni < 4; ++ni)                                    \
        acc[mi][ni] =                                                                     \
            __builtin_amdgcn_mfma_f32_16x16x32_bf16(afr[mi], bfr[ni], acc[mi][ni], 0, 0, 0); \
  }

#define GS_STEP8(AC, BC, SN, AN, BN_)                                                     \
  {                                                                                       \
    GS_STAGE(AN, BN_, (SN) * 32);                                                         \
    asm volatile("s_waitcnt vmcnt(8)" ::: "memory");                                      \
    __builtin_amdgcn_s_barrier();                                                         \
    GS_COMPUTE(AC, BC);                                                                   \
    __builtin_amdgcn_s_barrier();                                                         \
  }

  const int nst = 72;  // K=2304/32, divisible by 4
  GS_STAGE(sA0, sB0, 0);
  GS_STAGE(sA1, sB1, 32);
  for (int s4 = 0; s4 < nst - 4; s4 += 4) {
    GS_STEP8(sA0, sB0, s4 + 2, sA2, sB2);
    GS_STEP8(sA1, sB1, s4 + 3, sA3, sB3);
    GS_STEP8(sA2, sB2, s4 + 4, sA0, sB0);
    GS_STEP8(sA3, sB3, s4 + 5, sA1, sB1);
  }
  GS_STEP8(sA0, sB0, nst - 2, sA2, sB2);
  GS_STEP8(sA1, sB1, nst - 1, sA3, sB3);
  asm volatile("s_waitcnt vmcnt(4)" ::: "memory");
  __builtin_amdgcn_s_barrier();
  GS_COMPUTE(sA2, sB2);
  __builtin_amdgcn_s_barrier();
  asm volatile("s_waitcnt vmcnt(0)" ::: "memory");
  __builtin_amdgcn_s_barrier();
  GS_COMPUTE(sA3, sB3);
  __builtin_amdgcn_s_barrier();
#undef GS_STAGE
#undef GS_COMPUTE
#undef GS_STEP8

  // fused bias+BN2+ReLU epilogue -> act2T
  int trow = tid >> 3;
  int tcol16 = (tid & 7) * 16;
  int c0e = n0 + tcol16;
  float sc[16], sh[16];
#pragma unroll
  for (int q = 0; q < 4; ++q) {
    *(float4*)&sc[q * 4] = *(const float4*)(scale + c0e + q * 4);
    *(float4*)&sh[q * 4] = *(const float4*)(shift + c0e + q * 4);
  }
  int growBase = m0 + (trow >> 4) * 64 + (trow & 15);
#pragma unroll
  for (int mi = 0; mi < 4; ++mi) {
    __syncthreads();
#pragma unroll
    for (int ni = 0; ni < 4; ++ni)
#pragma unroll
      for (int reg = 0; reg < 4; ++reg)
        tbuf[(wm * 16 + quad * 4 + reg) * 132 + wn * 64 + ni * 16 + lane15] = acc[mi][ni][reg];
    __syncthreads();
    int gr = growBase + mi * 16;
    const float* lp = &tbuf[trow * 132 + tcol16];
    unsigned o[8];
#pragma unroll
    for (int j = 0; j < 8; ++j) {
      float lo = fmaxf(lp[2 * j] * sc[2 * j] + sh[2 * j], 0.f);
      float hi = fmaxf(lp[2 * j + 1] * sc[2 * j + 1] + sh[2 * j + 1], 0.f);
      o[j] = (unsigned)f2bf(lo) | ((unsigned)f2bf(hi) << 16);
    }
    unsigned short* op = outT + (size_t)gr * 256 + c0e;
    *(uint4*)(op) = uint4{o[0], o[1], o[2], o[3]};
    *(uint4*)(op + 8) = uint4{o[4], o[5], o[6], o[7]};
  }
}

// ---------------- final GEMM (1x1 conv #3), BN3 pre-folded, T4 pipeline + swizzle ----------------
__global__ __launch_bounds__(256) void gemm_res(
    const unsigned short* __restrict__ A, const unsigned short* __restrict__ Bm,
    float* __restrict__ outp, const float* __restrict__ shift3,
    const float* __restrict__ resid, int M, int N, int K, long bStrideB, long bStrideOut) {
  __shared__ __align__(16) char blob[16896];
  __shared__ __align__(16) unsigned short sA1[4096];
  __shared__ __align__(16) unsigned short sB1[4096];
  unsigned short* sA0 = (unsigned short*)blob;
  unsigned short* sB0 = (unsigned short*)(blob + 8192);
  float* tbuf = (float*)blob;
  int tid = threadIdx.x, lane = tid & 63, wv = tid >> 6;
  int z = blockIdx.z;
  const unsigned short* Bz = Bm + (size_t)z * bStrideB;
  int m0 = blockIdx.y * 128, n0 = blockIdx.x * 128;
  f32x4 acc[4][4] = {};
  int rowA = tid >> 2;
  int kcolS = (((tid & 3) ^ (rowA & 3))) * 8;   // pre-swizzled source col
  int wm = wv & 1, wn = wv >> 1;
  int lane15 = lane & 15, quad = lane >> 4, l3 = lane & 3;

#define GR_STAGE(dA, dB, K0)                                                              \
  {                                                                                       \
    int k0_ = (K0);                                                                       \
    _Pragma("unroll") for (int r = 0; r < 2; ++r) {                                       \
      const unsigned short* gp = A + (size_t)(m0 + r * 64 + rowA) * K + k0_ + kcolS;      \
      __builtin_amdgcn_global_load_lds((const __attribute__((address_space(1))) void*)gp, \
          (__attribute__((address_space(3))) void*)&(dA)[r * 2048 + wv * 512], 16, 0, 0); \
    }                                                                                     \
    _Pragma("unroll") for (int r = 0; r < 2; ++r) {                                       \
      const unsigned short* gp = Bz + (size_t)(n0 + r * 64 + rowA) * K + k0_ + kcolS;     \
      __builtin_amdgcn_global_load_lds((const __attribute__((address_space(1))) void*)gp, \
          (__attribute__((address_space(3))) void*)&(dB)[r * 2048 + wv * 512], 16, 0, 0); \
    }                                                                                     \
  }

#define GR_COMPUTE(dA, dB)                                                                \
  {                                                                                       \
    bf16x8 afr[4], bfr[4];                                                                \
    _Pragma("unroll") for (int mi = 0; mi < 4; ++mi)                                      \
      afr[mi] = *(const bf16x8*)&(dA)[(wm * 64 + mi * 16 + lane15) * 32 + (quad ^ l3) * 8]; \
    _Pragma("unroll") for (int ni = 0; ni < 4; ++ni)                                      \
      bfr[ni] = *(const bf16x8*)&(dB)[(wn * 64 + ni * 16 + lane15) * 32 + (quad ^ l3) * 8]; \
    _Pragma("unroll") for (int mi = 0; mi < 4; ++mi)                                      \
      _Pragma("unroll") for (int ni = 0; ni < 4; ++ni)                                    \
        acc[mi][ni] =                                                                     \
            __builtin_amdgcn_mfma_f32_16x16x32_bf16(afr[mi], bfr[ni], acc[mi][ni], 0, 0, 0); \
  }

  int nst = K >> 5;  // 8: even
  GR_STAGE(sA0, sB0, 0);
  for (int t = 0; t < nst; t += 2) {
    GR_STAGE(sA1, sB1, (t + 1) * 32);
    asm volatile("s_waitcnt vmcnt(4)" ::: "memory");
    __builtin_amdgcn_s_barrier();
    GR_COMPUTE(sA0, sB0);
    __builtin_amdgcn_s_barrier();
    if (t + 2 < nst) {
      GR_STAGE(sA0, sB0, (t + 2) * 32);
      asm volatile("s_waitcnt vmcnt(4)" ::: "memory");
    } else {
      asm volatile("s_waitcnt vmcnt(0)" ::: "memory");
    }
    __builtin_amdgcn_s_barrier();
    GR_COMPUTE(sA1, sB1);
    __builtin_amdgcn_s_barrier();
  }
#undef GR_STAGE
#undef GR_COMPUTE

  float* outF = outp + (size_t)z * bStrideOut;
  const float* res = resid + (size_t)z * bStrideOut;
  int trow = tid >> 3;
  int tcol = (tid & 7) * 4;
  int growBase = m0 + (trow >> 4) * 64 + (trow & 15);
#pragma unroll
  for (int mi = 0; mi < 4; ++mi) {
    __syncthreads();
#pragma unroll
    for (int ni = 0; ni < 4; ++ni)
#pragma unroll
      for (int reg = 0; reg < 4; ++reg)
        tbuf[(wm * 16 + quad * 4 + reg) * 132 + wn * 64 + ni * 16 + lane15] = acc[mi][ni][reg];
    __syncthreads();
    int gr = growBase + mi * 16;
    float sh = shift3[gr];
    const float* rp = res + (size_t)gr * N + n0 + tcol;
    float* op = outF + (size_t)gr * N + n0 + tcol;
    const float* lp = &tbuf[trow * 132 + tcol];
#pragma unroll
    for (int j = 0; j < 4; ++j) {
      float4 rv = *(const float4*)(rp + j * 32);
      float4 lv = *(const float4*)(lp + j * 32);
      float4 ov;
      ov.x = fmaxf(lv.x + sh + rv.x, 0.f);
      ov.y = fmaxf(lv.y + sh + rv.y, 0.f);
      ov.z = fmaxf(lv.z + sh + rv.z, 0.f);
      ov.w = fmaxf(lv.w + sh + rv.w, 0.f);
      *(float4*)(op + j * 32) = ov;
    }
  }
}

// ---------------- offset conv as MFMA GEMM over padded act1P, depth-2 prefetch ----------------
__global__ __launch_bounds__(256) void off_gemm(const unsigned short* __restrict__ actP,
                                                const unsigned short* __restrict__ wob,
                                                const float* __restrict__ boff,
                                                float* __restrict__ offsP) {
  __shared__ __align__(16) unsigned short sA0[4096];
  __shared__ __align__(16) unsigned short sA1[4096];
  __shared__ __align__(16) unsigned short sA2[4096];
  __shared__ __align__(16) unsigned short sA3[4096];
  __shared__ __align__(16) unsigned short sB0[2048];
  __shared__ __align__(16) unsigned short sB1[2048];
  __shared__ __align__(16) unsigned short sB2[2048];
  __shared__ __align__(16) unsigned short sB3[2048];
  int tid = threadIdx.x, lane = tid & 63, wv = tid >> 6;
  int m0 = blockIdx.x * 64;
  int lane15 = lane & 15, quad8 = (lane >> 4) * 8;
  int rowA = tid >> 3;
  int kc = (tid & 7) * 8;

  const unsigned short* baseA[2];
#pragma unroll
  for (int r = 0; r < 2; ++r) {
    int row = m0 + r * 32 + rowA;
    int b = row >> 12, p = row & 4095;
    baseA[r] = actP + (((size_t)(b * 68) + (p >> 6) + 2) * 68 + (p & 63) + 2) * 256 + kc;
  }
  const unsigned short* baseB = wob + (size_t)rowA * 2304 + kc;

  f32x4 acc[2] = {};

#define OG_STAGE(dA, dB, S)                                                               \
  {                                                                                       \
    int s_ = (S); int kk_ = s_ >> 2; int c0_ = (s_ & 3) * 64;                             \
    long shift_ = (long)(((kk_ / 3) * 2 - 2) * 68 + ((kk_ % 3) * 2 - 2));                 \
    _Pragma("unroll") for (int r = 0; r < 2; ++r) {                                       \
      const unsigned short* gp = baseA[r] + shift_ * 256 + c0_;                           \
      __builtin_amdgcn_global_load_lds((const __attribute__((address_space(1))) void*)gp, \
          (__attribute__((address_space(3))) void*)&(dA)[r * 2048 + wv * 512], 16, 0, 0); \
    }                                                                                     \
    {                                                                                     \
      const unsigned short* gp = baseB + kk_ * 256 + c0_;                                 \
      __builtin_amdgcn_global_load_lds((const __attribute__((address_space(1))) void*)gp, \
          (__attribute__((address_space(3))) void*)&(dB)[wv * 512], 16, 0, 0);            \
    }                                                                                     \
  }

#define OG_COMPUTE(dA, dB)                                                                \
  {                                                                                       \
    bf16x8 afr[2], bfr[2][2];                                                             \
    _Pragma("unroll") for (int kq = 0; kq < 2; ++kq) {                                    \
      afr[kq] = *(const bf16x8*)&(dA)[(wv * 16 + lane15) * 64 + kq * 32 + quad8];         \
      _Pragma("unroll") for (int ni = 0; ni < 2; ++ni)                                    \
        bfr[kq][ni] = *(const bf16x8*)&(dB)[(ni * 16 + lane15) * 64 + kq * 32 + quad8];   \
    }                                                                                     \
    _Pragma("unroll") for (int kq = 0; kq < 2; ++kq)                                      \
      _Pragma("unroll") for (int ni = 0; ni < 2; ++ni)                                    \
        acc[ni] = __builtin_amdgcn_mfma_f32_16x16x32_bf16(afr[kq], bfr[kq][ni], acc[ni], 0, 0, 0); \
  }

#define OG_STEP6(AC, BC, SN, AN, BN_)                                                     \
  {                                                                                       \
    OG_STAGE(AN, BN_, SN);                                                                \
    asm volatile("s_waitcnt vmcnt(6)" ::: "memory");                                      \
    __builtin_amdgcn_s_barrier();                                                         \
    OG_COMPUTE(AC, BC);                                                                   \
    __builtin_amdgcn_s_barrier();                                                         \
  }

  OG_STAGE(sA0, sB0, 0);
  OG_STAGE(sA1, sB1, 1);
  for (int s4 = 0; s4 < 32; s4 += 4) {
    OG_STEP6(sA0, sB0, s4 + 2, sA2, sB2);
    OG_STEP6(sA1, sB1, s4 + 3, sA3, sB3);
    OG_STEP6(sA2, sB2, s4 + 4, sA0, sB0);
    OG_STEP6(sA3, sB3, s4 + 5, sA1, sB1);
  }
  OG_STEP6(sA0, sB0, 34, sA2, sB2);
  OG_STEP6(sA1, sB1, 35, sA3, sB3);
  asm volatile("s_waitcnt vmcnt(3)" ::: "memory");
  __builtin_amdgcn_s_barrier();
  OG_COMPUTE(sA2, sB2);
  __builtin_amdgcn_s_barrier();
  asm volatile("s_waitcnt vmcnt(0)" ::: "memory");
  __builtin_amdgcn_s_barrier();
  OG_COMPUTE(sA3, sB3);
#undef OG_STAGE
#undef OG_COMPUTE
#undef OG_STEP6

#pragma unroll
  for (int ni = 0; ni < 2; ++ni) {
    int o = ni * 16 + lane15;
    if (o < 18) {
      float bo = boff[o];
#pragma unroll
      for (int reg = 0; reg < 4; ++reg) {
        int row = m0 + wv * 16 + (lane >> 4) * 4 + reg;
        offsP[(size_t)row * 18 + o] = acc[ni][reg] + bo;
      }
    }
  }
}

// ---------------- bilinear im2col, vectorized: 32 lanes x 8ch per pixel ----------------
__global__ __launch_bounds__(256) void deform_sample(const unsigned short* __restrict__ act1T,
                                                     const float* __restrict__ offsP,
                                                     unsigned short* __restrict__ S) {
  int g = threadIdx.x >> 5, t = threadIdx.x & 31;
  int idx = blockIdx.x * 8 + g;
  int b = idx >> 12, p = idx & 4095;
  int h = p >> 6, w = p & 63;
  const unsigned short* actb = act1T + (size_t)b * 4096 * 256 + t * 8;
  unsigned short* Sp = S + (size_t)idx * 2304 + t * 8;
  float ov = (t < 18) ? offsP[(size_t)idx * 18 + t] : 0.f;
#pragma unroll
  for (int kk = 0; kk < 9; ++kk) {
    float offy = __shfl(ov, 2 * kk, 32);
    float offx = __shfl(ov, 2 * kk + 1, 32);
    float py = (float)(h + (kk / 3) * 2 - 2) + offy;
    float px = (float)(w + (kk % 3) * 2 - 2) + offx;
    float fy = floorf(py), fx = floorf(px);
    int y0 = (int)fy, x0 = (int)fx;
    float wy = py - fy, wx = px - fx;
    bool yv0 = (y0 >= 0 && y0 < 64), yv1 = (y0 >= -1 && y0 < 63);
    bool xv0 = (x0 >= 0 && x0 < 64), xv1 = (x0 >= -1 && x0 < 63);
    const unsigned short* cb = actb + (y0 * 64 + x0) * 256;
    uint4 q00{0,0,0,0}, q01{0,0,0,0}, q10{0,0,0,0}, q11{0,0,0,0};
    if (yv0 && xv0) q00 = *(const uint4*)(cb);
    if (yv0 && xv1) q01 = *(const uint4*)(cb + 256);
    if (yv1 && xv0) q10 = *(const uint4*)(cb + 64 * 256);
    if (yv1 && xv1) q11 = *(const uint4*)(cb + 64 * 256 + 256);
    float w00 = (1.f - wy) * (1.f - wx), w01 = (1.f - wy) * wx;
    float w10 = wy * (1.f - wx), w11 = wy * wx;
    unsigned u00[4] = {q00.x, q00.y, q00.z, q00.w};
    unsigned u01[4] = {q01.x, q01.y, q01.z, q01.w};
    unsigned u10[4] = {q10.x, q10.y, q10.z, q10.w};
    unsigned u11[4] = {q11.x, q11.y, q11.z, q11.w};
    unsigned out[4];
#pragma unroll
    for (int j = 0; j < 4; ++j) {
      float lo = bf2f((unsigned short)(u00[j] & 0xffffu)) * w00 +
                 bf2f((unsigned short)(u01[j] & 0xffffu)) * w01 +
                 bf2f((unsigned short)(u10[j] & 0xffffu)) * w10 +
                 bf2f((unsigned short)(u11[j] & 0xffffu)) * w11;
      float hi = bf2f((unsigned short)(u00[j] >> 16)) * w00 +
                 bf2f((unsigned short)(u01[j] >> 16)) * w01 +
                 bf2f((unsigned short)(u10[j] >> 16)) * w10 +
                 bf2f((unsigned short)(u11[j] >> 16)) * w11;
      out[j] = (unsigned)f2bf(lo) | ((unsigned)f2bf(hi) << 16);
    }
    *(uint4*)(Sp + kk * 256) = uint4{out[0], out[1], out[2], out[3]};
  }
}

extern "C" void kernel_launch(void* const* d_in, const int* in_sizes, int n_in,
                              void* d_out, int out_size, void* d_ws, size_t ws_size,
                              hipStream_t stream) {
  const float* x      = (const float*)d_in[0];
  const float* w1     = (const float*)d_in[1];
  const float* gamma1 = (const float*)d_in[2];
  const float* beta1  = (const float*)d_in[3];
  const float* mean1  = (const float*)d_in[4];
  const float* var1   = (const float*)d_in[5];
  const float* woff   = (const float*)d_in[6];
  const float* boff   = (const float*)d_in[7];
  const float* w2     = (const float*)d_in[8];
  const float* bconv2 = (const float*)d_in[9];
  const float* gamma2 = (const float*)d_in[10];
  const float* beta2  = (const float*)d_in[11];
  const float* mean2  = (const float*)d_in[12];
  const float* var2   = (const float*)d_in[13];
  const float* w3     = (const float*)d_in[14];
  const float* gamma3 = (const float*)d_in[15];
  const float* beta3  = (const float*)d_in[16];
  const float* mean3  = (const float*)d_in[17];
  const float* var3   = (const float*)d_in[18];

  char* ws = (char*)d_ws;
  unsigned short* act1T = (unsigned short*)(ws + 33554432);      //  8,388,608
  unsigned short* act2T = (unsigned short*)(ws + 41943040);      //  8,388,608
  unsigned short* S     = (unsigned short*)(ws + 50331648);      // 75,497,472 (ends 125,829,120)
  float*          offs  = (float*)(ws + 125829120);              //  1,179,648
  unsigned short* w1b   = (unsigned short*)(ws + 127008768);     //    524,288
  unsigned short* w2r   = (unsigned short*)(ws + 127533056);     //  1,179,648
  unsigned short* w3b   = (unsigned short*)(ws + 128712704);     //    524,288
  float*          bnS1  = (float*)(ws + 129236992);              //      1,024
  float*          bnH1  = (float*)(ws + 129238016);              //      1,024
  float*          bnS2  = (float*)(ws + 129239040);              //      1,024
  float*          bnH2  = (float*)(ws + 129240064);              //      1,024
  float*          shift3= (float*)(ws + 129241088);              //      4,096
  // aliased (non-overlapping lifetimes):
  unsigned short* act1P = S;                                  // 9.47 MB at S base; dead before S written
  unsigned short* wob   = act2T;                              // 147 KB; dead before gemm2f writes act2T

  prep_all<<<4909, 256, 0, stream>>>(w1, w2, woff, w3,
                                     gamma1, beta1, mean1, var1,
                                     gamma2, beta2, mean2, var2, bconv2,
                                     gamma3, beta3, mean3, var3,
                                     w1b, w2r, (uint4*)act1P, wob, w3b, shift3,
                                     bnS1, bnH1, bnS2, bnH2);

  // GEMM1 (K=1024, full) fused x-transpose + BN1+ReLU -> act1T + padded act1P
  gemm1f<<<dim3(2, 128), 256, 0, stream>>>(x, w1b, bnS1, bnH1, act1T, act1P);

  off_gemm<<<256, 256, 0, stream>>>(act1P, wob, boff, offs);
  deform_sample<<<dim3(2048), 256, 0, stream>>>(act1T, offs, S);

  // GEMM2 (K=2304, full) depth-2 + fused bias+BN2+ReLU -> act2T
  gemm2f<<<dim3(2, 128), 256, 0, stream>>>(S, w2r, bnS2, bnH2, act2T);

  // GEMM3: out = relu(w3s @ act2T^T + shift3 + x)
  gemm_res<<<dim3(32, 8, 4), 256, 0, stream>>>(w3b, act2T, (float*)d_out, shift3, x,
                                               1024, 4096, 256, 4096L * 256, 4194304L);
}

// Round 13
// 270.731 us; speedup vs baseline: 1.0066x; 1.0066x over previous
//
#include <hip/hip_runtime.h>

#define EPS_BN 1e-5f

typedef __bf16 bf16x8 __attribute__((ext_vector_type(8)));
typedef float f32x4 __attribute__((ext_vector_type(4)));

__device__ __forceinline__ unsigned short f2bf(float f) {
  union { float f; unsigned u; } v; v.f = f;
  unsigned r = v.u + 0x7fffu + ((v.u >> 16) & 1u);
  return (unsigned short)(r >> 16);
}
__device__ __forceinline__ float bf2f(unsigned short h) {
  union { unsigned u; float f; } v; v.u = ((unsigned)h) << 16;
  return v.f;
}

// ---------------- fused prep (act1P: pad-ring zeroing only; interior written by epi_bn1) ----------------
__global__ __launch_bounds__(256) void prep_all(
    const float* __restrict__ w1, const float* __restrict__ w2, const float* __restrict__ woff,
    const float* __restrict__ w3,
    const float* g1, const float* b1, const float* m1, const float* v1,
    const float* g2, const float* b2, const float* m2, const float* v2, const float* bconv2,
    const float* g3, const float* b3, const float* m3, const float* v3,
    unsigned short* __restrict__ w1b, unsigned short* __restrict__ w2r,
    uint4* __restrict__ act1Pz, unsigned short* __restrict__ wob,
    unsigned short* __restrict__ w3b, float* __restrict__ shift3,
    float* s1, float* h1, float* s2, float* h2) {
  int bid = blockIdx.x, tid = threadIdx.x;
  if (bid < 1024) {
    int i = bid * 256 + tid;
    w1b[i] = f2bf(w1[i]);
  } else if (bid < 3328) {
    int i = (bid - 1024) * 256 + tid;
    int o = i / 2304, r = i % 2304;
    int kk = r / 256, c = r % 256;
    w2r[i] = f2bf(w2[(size_t)o * 2304 + c * 9 + kk]);
  } else if (bid < 3592) {
    // zero the 2-wide pad ring of act1P: 4 batches x 528 ring cells x 32 uint4
    int i = (bid - 3328) * 256 + tid;        // 0..67583
    int cell = i >> 5, q = i & 31;
    int b = cell / 528, r = cell - b * 528;
    int row, col;
    if (r < 136) { row = r / 68; col = r % 68; }
    else if (r < 272) { int rr = r - 136; row = 66 + rr / 68; col = rr % 68; }
    else { int rr = r - 272; row = 2 + (rr >> 2); int c4 = rr & 3; col = (c4 < 2) ? c4 : c4 + 64; }
    act1Pz[(((size_t)(b * 68) + row) * 68 + col) * 32 + q] = uint4{0, 0, 0, 0};
  } else if (bid < 3880) {
    int i = (bid - 3592) * 256 + tid;
    int o = i / 2304, r = i % 2304;
    int kk = r / 256, c = r % 256;
    wob[i] = (o < 18) ? f2bf(woff[(size_t)o * 2304 + c * 9 + kk]) : (unsigned short)0;
  } else if (bid < 4904) {
    int i = (bid - 3880) * 256 + tid;
    int o = i >> 8;
    float sc = rsqrtf(v3[o] + EPS_BN) * g3[o];
    w3b[i] = f2bf(w3[i] * sc);
  } else if (bid < 4908) {
    int c = (bid - 4904) * 256 + tid;
    float sc = rsqrtf(v3[c] + EPS_BN) * g3[c];
    shift3[c] = b3[c] - m3[c] * sc;
  } else {
    int c = tid;
    float sc1 = rsqrtf(v1[c] + EPS_BN) * g1[c];
    s1[c] = sc1; h1[c] = b1[c] - m1[c] * sc1;
    float sc2 = rsqrtf(v2[c] + EPS_BN) * g2[c];
    s2[c] = sc2; h2[c] = b2[c] + (bconv2[c] - m2[c]) * sc2;
  }
}

// ---------------- GEMM1 with fused x-transpose: A staged from f32 x (c-major) ----------------
// Swizzled LDS (slot ^= row&3 within 64B rows) on A ds_write, B staging source, and reads.
__global__ __launch_bounds__(256) void gemm1_x(
    const float* __restrict__ x, const unsigned short* __restrict__ Bm,
    unsigned short* __restrict__ part, int KH) {
  __shared__ __align__(16) char blob[16896];              // sA0|sB0, tbuf aliases
  __shared__ __align__(16) unsigned short sA1[4096];
  __shared__ __align__(16) unsigned short sB1[4096];
  unsigned short* sA0 = (unsigned short*)blob;
  unsigned short* sB0 = (unsigned short*)(blob + 8192);
  float* tbuf = (float*)blob;                             // epilogue only
  int tid = threadIdx.x, lane = tid & 63, wv = tid >> 6;
  int z = blockIdx.z;
  int m0 = blockIdx.y * 128, n0 = blockIdx.x * 128;
  f32x4 acc[4][4] = {};
  // B staging mapping (pre-swizzled source col)
  int rowB = tid >> 2;
  int kcolBs = (((tid & 3) ^ (rowB & 3))) * 8;
  // A staging mapping: 2 threads/row, 16 ch each; swizzled write slots
  int px = tid & 127, chalf = tid >> 7;
  int s0w = (chalf * 2) ^ (px & 3), s1w = (chalf * 2 + 1) ^ (px & 3);
  int bb = m0 >> 12, p0 = m0 & 4095;
  const float* xa = x + (size_t)bb * 4194304 + (size_t)(chalf * 16) * 4096 + (p0 + px);
  int wm = wv & 1, wn = wv >> 1;
  int lane15 = lane & 15, quad = lane >> 4, l3 = lane & 3;

  float va[16];

#define G1_ISSUE_A(K0)                                                                    \
  {                                                                                       \
    const float* xp = xa + (size_t)(K0) * 4096;                                           \
    _Pragma("unroll") for (int j = 0; j < 16; ++j) va[j] = xp[(size_t)j * 4096];          \
  }

#define G1_ISSUE_B(DB, K0)                                                                \
  {                                                                                       \
    _Pragma("unroll") for (int r = 0; r < 2; ++r) {                                       \
      const unsigned short* gp = Bm + (size_t)(n0 + r * 64 + rowB) * 1024 + (K0) + kcolBs;\
      __builtin_amdgcn_global_load_lds((const __attribute__((address_space(1))) void*)gp, \
          (__attribute__((address_space(3))) void*)&(DB)[r * 2048 + wv * 512], 16, 0, 0); \
    }                                                                                     \
  }

#define G1_CVT_WRITE(DA)                                                                  \
  {                                                                                       \
    unsigned o8[8];                                                                       \
    _Pragma("unroll") for (int j = 0; j < 8; ++j)                                         \
      o8[j] = (unsigned)f2bf(va[2 * j]) | ((unsigned)f2bf(va[2 * j + 1]) << 16);          \
    *(uint4*)((DA) + px * 32 + s0w * 8) = uint4{o8[0], o8[1], o8[2], o8[3]};              \
    *(uint4*)((DA) + px * 32 + s1w * 8) = uint4{o8[4], o8[5], o8[6], o8[7]};              \
  }

#define G1_COMPUTE(DA, DB)                                                                \
  {                                                                                       \
    bf16x8 afr[4], bfr[4];                                                                \
    _Pragma("unroll") for (int mi = 0; mi < 4; ++mi)                                      \
      afr[mi] = *(const bf16x8*)&(DA)[(wm * 64 + mi * 16 + lane15) * 32 + (quad ^ l3) * 8]; \
    _Pragma("unroll") for (int ni = 0; ni < 4; ++ni)                                      \
      bfr[ni] = *(const bf16x8*)&(DB)[(wn * 64 + ni * 16 + lane15) * 32 + (quad ^ l3) * 8]; \
    _Pragma("unroll") for (int mi = 0; mi < 4; ++mi)                                      \
      _Pragma("unroll") for (int ni = 0; ni < 4; ++ni)                                    \
        acc[mi][ni] =                                                                     \
            __builtin_amdgcn_mfma_f32_16x16x32_bf16(afr[mi], bfr[ni], acc[mi][ni], 0, 0, 0); \
  }

#define G1_BODY(K0, AC, BC, AN, BN_)                                                      \
  {                                                                                       \
    G1_ISSUE_A(K0);                                                                       \
    G1_ISSUE_B(BN_, K0);                                                                  \
    asm volatile("s_waitcnt vmcnt(18)" ::: "memory");                                     \
    asm volatile("s_waitcnt lgkmcnt(0)" ::: "memory");                                    \
    __builtin_amdgcn_s_barrier();                                                         \
    G1_COMPUTE(AC, BC);                                                                   \
    asm volatile("s_waitcnt vmcnt(2)" ::: "memory");                                      \
    G1_CVT_WRITE(AN);                                                                     \
    __builtin_amdgcn_s_barrier();                                                         \
  }

  int kbase = z * KH;
  int nst = KH >> 5;  // 16: even
  G1_ISSUE_A(kbase);
  G1_ISSUE_B(sB0, kbase);
  asm volatile("s_waitcnt vmcnt(2)" ::: "memory");
  G1_CVT_WRITE(sA0);
  for (int t = 0; t + 2 < nst; t += 2) {
    G1_BODY(kbase + (t + 1) * 32, sA0, sB0, sA1, sB1);
    G1_BODY(kbase + (t + 2) * 32, sA1, sB1, sA0, sB0);
  }
  G1_BODY(kbase + (nst - 1) * 32, sA0, sB0, sA1, sB1);
  asm volatile("s_waitcnt vmcnt(0)" ::: "memory");
  asm volatile("s_waitcnt lgkmcnt(0)" ::: "memory");
  __builtin_amdgcn_s_barrier();
  G1_COMPUTE(sA1, sB1);
#undef G1_ISSUE_A
#undef G1_ISSUE_B
#undef G1_CVT_WRITE
#undef G1_COMPUTE
#undef G1_BODY

  // vectorized epilogue -> z-partial
  unsigned short* outH = part + (size_t)z * 16384 * 256;
  int trow = tid >> 3;
  int tcol16 = (tid & 7) * 16;
  int growBase = m0 + (trow >> 4) * 64 + (trow & 15);
#pragma unroll
  for (int mi = 0; mi < 4; ++mi) {
    __syncthreads();
#pragma unroll
    for (int ni = 0; ni < 4; ++ni)
#pragma unroll
      for (int reg = 0; reg < 4; ++reg)
        tbuf[(wm * 16 + quad * 4 + reg) * 132 + wn * 64 + ni * 16 + lane15] = acc[mi][ni][reg];
    __syncthreads();
    int gr = growBase + mi * 16;
    const float* lp = &tbuf[trow * 132 + tcol16];
    unsigned o[8];
#pragma unroll
    for (int j = 0; j < 8; ++j)
      o[j] = (unsigned)f2bf(lp[2 * j]) | ((unsigned)f2bf(lp[2 * j + 1]) << 16);
    unsigned short* op = outH + (size_t)gr * 256 + n0 + tcol16;
    *(uint4*)(op) = uint4{o[0], o[1], o[2], o[3]};
    *(uint4*)(op + 8) = uint4{o[4], o[5], o[6], o[7]};
  }
}

// ---------------- GEMM2: BK=64 superstep, swizzled LDS (slot ^= row&7), vmcnt(8) ----------------
__global__ __launch_bounds__(256) void gemm_split(
    const unsigned short* __restrict__ A, const unsigned short* __restrict__ Bm,
    unsigned short* __restrict__ part, int M, int N, int K, int KH) {
  __shared__ __align__(16) char blob[32768];              // sA0|sB0 (16K each), tbuf aliases
  __shared__ __align__(16) unsigned short sA1[8192];
  __shared__ __align__(16) unsigned short sB1[8192];
  unsigned short* sA0 = (unsigned short*)blob;
  unsigned short* sB0 = (unsigned short*)(blob + 16384);
  float* tbuf = (float*)blob;                             // epilogue only
  int tid = threadIdx.x, lane = tid & 63, wv = tid >> 6;
  int z = blockIdx.z;
  int m0 = blockIdx.y * 128, n0 = blockIdx.x * 128;
  f32x4 acc[4][4] = {};
  int rowS = tid >> 3;               // 0..31 staging row within call
  int colS = (((tid & 7) ^ (rowS & 7))) * 8;  // pre-swizzled source col (elements)
  int wm = wv & 1, wn = wv >> 1;
  int lane15 = lane & 15, quad = lane >> 4, l7 = lane & 7;

#define GS_STAGE(dA, dB, K0)                                                              \
  {                                                                                       \
    int k0_ = (K0);                                                                       \
    _Pragma("unroll") for (int r = 0; r < 4; ++r) {                                       \
      const unsigned short* gp = A + (size_t)(m0 + r * 32 + rowS) * K + k0_ + colS;       \
      __builtin_amdgcn_global_load_lds((const __attribute__((address_space(1))) void*)gp, \
          (__attribute__((address_space(3))) void*)&(dA)[r * 2048 + wv * 512], 16, 0, 0); \
    }                                                                                     \
    _Pragma("unroll") for (int r = 0; r < 4; ++r) {                                       \
      const unsigned short* gp = Bm + (size_t)(n0 + r * 32 + rowS) * K + k0_ + colS;      \
      __builtin_amdgcn_global_load_lds((const __attribute__((address_space(1))) void*)gp, \
          (__attribute__((address_space(3))) void*)&(dB)[r * 2048 + wv * 512], 16, 0, 0); \
    }                                                                                     \
  }

#define GS_COMPUTE(dA, dB)                                                                \
  {                                                                                       \
    _Pragma("unroll") for (int kq = 0; kq < 2; ++kq) {                                    \
      bf16x8 afr[4], bfr[4];                                                              \
      _Pragma("unroll") for (int mi = 0; mi < 4; ++mi)                                    \
        afr[mi] = *(const bf16x8*)&(dA)[(wm * 64 + mi * 16 + lane15) * 64 +               \
                                        ((kq * 4 + quad) ^ l7) * 8];                      \
      _Pragma("unroll") for (int ni = 0; ni < 4; ++ni)                                    \
        bfr[ni] = *(const bf16x8*)&(dB)[(wn * 64 + ni * 16 + lane15) * 64 +               \
                                        ((kq * 4 + quad) ^ l7) * 8];                      \
      _Pragma("unroll") for (int mi = 0; mi < 4; ++mi)                                    \
        _Pragma("unroll") for (int ni = 0; ni < 4; ++ni)                                  \
          acc[mi][ni] =                                                                   \
              __builtin_amdgcn_mfma_f32_16x16x32_bf16(afr[mi], bfr[ni], acc[mi][ni], 0, 0, 0); \
    }                                                                                     \
  }

  int kbase = z * KH;
  int nst = KH >> 6;  // 18 (GEMM2 z=2): even
  GS_STAGE(sA0, sB0, kbase);
  for (int t = 0; t < nst; t += 2) {
    GS_STAGE(sA1, sB1, kbase + (t + 1) * 64);
    asm volatile("s_waitcnt vmcnt(8)" ::: "memory");
    __builtin_amdgcn_s_barrier();
    GS_COMPUTE(sA0, sB0);
    __builtin_amdgcn_s_barrier();
    if (t + 2 < nst) {
      GS_STAGE(sA0, sB0, kbase + (t + 2) * 64);
      asm volatile("s_waitcnt vmcnt(8)" ::: "memory");
    } else {
      asm volatile("s_waitcnt vmcnt(0)" ::: "memory");
    }
    __builtin_amdgcn_s_barrier();
    GS_COMPUTE(sA1, sB1);
    __builtin_amdgcn_s_barrier();
  }
#undef GS_STAGE
#undef GS_COMPUTE

  // vectorized epilogue: LDS-transpose each 32-row chunk, pack 16ch/thread -> 2 uint4 stores
  unsigned short* outH = part + (size_t)z * M * N;
  int trow = tid >> 3;              // 0..31
  int tcol16 = (tid & 7) * 16;      // 0..112
  int growBase = m0 + (trow >> 4) * 64 + (trow & 15);
#pragma unroll
  for (int mi = 0; mi < 4; ++mi) {
    __syncthreads();
#pragma unroll
    for (int ni = 0; ni < 4; ++ni)
#pragma unroll
      for (int reg = 0; reg < 4; ++reg)
        tbuf[(wm * 16 + quad * 4 + reg) * 132 + wn * 64 + ni * 16 + lane15] = acc[mi][ni][reg];
    __syncthreads();
    int gr = growBase + mi * 16;
    const float* lp = &tbuf[trow * 132 + tcol16];
    unsigned o[8];
#pragma unroll
    for (int j = 0; j < 8; ++j)
      o[j] = (unsigned)f2bf(lp[2 * j]) | ((unsigned)f2bf(lp[2 * j + 1]) << 16);
    unsigned short* op = outH + (size_t)gr * 256 + n0 + tcol16;
    *(uint4*)(op) = uint4{o[0], o[1], o[2], o[3]};
    *(uint4*)(op + 8) = uint4{o[4], o[5], o[6], o[7]};
  }
}

// ---------------- epilogue: sum NS bf16 partials, folded BN + ReLU -> bf16 (+opt padded copy) ----------------
template <int NS, int PAD>
__global__ __launch_bounds__(256) void epi_bn(const unsigned short* __restrict__ part,
                                              const float* __restrict__ scale,
                                              const float* __restrict__ shift,
                                              unsigned short* __restrict__ outT,
                                              unsigned short* __restrict__ outP) {
  int gid = blockIdx.x * 256 + threadIdx.x;   // 16384*32
  int row = gid >> 5, c0 = (gid & 31) * 8;
  float v[8] = {};
#pragma unroll
  for (int s = 0; s < NS; ++s) {
    uint4 q = *(const uint4*)(part + (size_t)s * 16384 * 256 + (size_t)row * 256 + c0);
    unsigned u[4] = {q.x, q.y, q.z, q.w};
#pragma unroll
    for (int j = 0; j < 4; ++j) {
      v[2 * j]     += bf2f((unsigned short)(u[j] & 0xffffu));
      v[2 * j + 1] += bf2f((unsigned short)(u[j] >> 16));
    }
  }
  float sc[8], sh[8];
  *(float4*)&sc[0] = *(const float4*)(scale + c0); *(float4*)&sc[4] = *(const float4*)(scale + c0 + 4);
  *(float4*)&sh[0] = *(const float4*)(shift + c0); *(float4*)&sh[4] = *(const float4*)(shift + c0 + 4);
  unsigned o[4];
#pragma unroll
  for (int j = 0; j < 4; ++j) {
    float lo = fmaxf(v[2 * j] * sc[2 * j] + sh[2 * j], 0.f);
    float hi = fmaxf(v[2 * j + 1] * sc[2 * j + 1] + sh[2 * j + 1], 0.f);
    o[j] = (unsigned)f2bf(lo) | ((unsigned)f2bf(hi) << 16);
  }
  uint4 pk{o[0], o[1], o[2], o[3]};
  *(uint4*)(outT + (size_t)row * 256 + c0) = pk;
  if constexpr (PAD) {
    int bb = row >> 12, p = row & 4095;
    *(uint4*)(outP + (((size_t)(bb * 68) + (p >> 6) + 2) * 68 + (p & 63) + 2) * 256 + c0) = pk;
  }
}

// ---------------- final GEMM (1x1 conv #3), BN3 pre-folded, T4 pipeline + swizzle ----------------
__global__ __launch_bounds__(256) void gemm_res(
    const unsigned short* __restrict__ A, const unsigned short* __restrict__ Bm,
    float* __restrict__ outp, const float* __restrict__ shift3,
    const float* __restrict__ resid, int M, int N, int K, long bStrideB, long bStrideOut) {
  __shared__ __align__(16) char blob[16896];
  __shared__ __align__(16) unsigned short sA1[4096];
  __shared__ __align__(16) unsigned short sB1[4096];
  unsigned short* sA0 = (unsigned short*)blob;
  unsigned short* sB0 = (unsigned short*)(blob + 8192);
  float* tbuf = (float*)blob;
  int tid = threadIdx.x, lane = tid & 63, wv = tid >> 6;
  int z = blockIdx.z;
  const unsigned short* Bz = Bm + (size_t)z * bStrideB;
  int m0 = blockIdx.y * 128, n0 = blockIdx.x * 128;
  f32x4 acc[4][4] = {};
  int rowA = tid >> 2;
  int kcolS = (((tid & 3) ^ (rowA & 3))) * 8;   // pre-swizzled source col
  int wm = wv & 1, wn = wv >> 1;
  int lane15 = lane & 15, quad = lane >> 4, l3 = lane & 3;

#define GR_STAGE(dA, dB, K0)                                                              \
  {                                                                                       \
    int k0_ = (K0);                                                                       \
    _Pragma("unroll") for (int r = 0; r < 2; ++r) {                                       \
      const unsigned short* gp = A + (size_t)(m0 + r * 64 + rowA) * K + k0_ + kcolS;      \
      __builtin_amdgcn_global_load_lds((const __attribute__((address_space(1))) void*)gp, \
          (__attribute__((address_space(3))) void*)&(dA)[r * 2048 + wv * 512], 16, 0, 0); \
    }                                                                                     \
    _Pragma("unroll") for (int r = 0; r < 2; ++r) {                                       \
      const unsigned short* gp = Bz + (size_t)(n0 + r * 64 + rowA) * K + k0_ + kcolS;     \
      __builtin_amdgcn_global_load_lds((const __attribute__((address_space(1))) void*)gp, \
          (__attribute__((address_space(3))) void*)&(dB)[r * 2048 + wv * 512], 16, 0, 0); \
    }                                                                                     \
  }

#define GR_COMPUTE(dA, dB)                                                                \
  {                                                                                       \
    bf16x8 afr[4], bfr[4];                                                                \
    _Pragma("unroll") for (int mi = 0; mi < 4; ++mi)                                      \
      afr[mi] = *(const bf16x8*)&(dA)[(wm * 64 + mi * 16 + lane15) * 32 + (quad ^ l3) * 8]; \
    _Pragma("unroll") for (int ni = 0; ni < 4; ++ni)                                      \
      bfr[ni] = *(const bf16x8*)&(dB)[(wn * 64 + ni * 16 + lane15) * 32 + (quad ^ l3) * 8]; \
    _Pragma("unroll") for (int mi = 0; mi < 4; ++mi)                                      \
      _Pragma("unroll") for (int ni = 0; ni < 4; ++ni)                                    \
        acc[mi][ni] =                                                                     \
            __builtin_amdgcn_mfma_f32_16x16x32_bf16(afr[mi], bfr[ni], acc[mi][ni], 0, 0, 0); \
  }

  int nst = K >> 5;  // 8: even
  GR_STAGE(sA0, sB0, 0);
  for (int t = 0; t < nst; t += 2) {
    GR_STAGE(sA1, sB1, (t + 1) * 32);
    asm volatile("s_waitcnt vmcnt(4)" ::: "memory");
    __builtin_amdgcn_s_barrier();
    GR_COMPUTE(sA0, sB0);
    __builtin_amdgcn_s_barrier();
    if (t + 2 < nst) {
      GR_STAGE(sA0, sB0, (t + 2) * 32);
      asm volatile("s_waitcnt vmcnt(4)" ::: "memory");
    } else {
      asm volatile("s_waitcnt vmcnt(0)" ::: "memory");
    }
    __builtin_amdgcn_s_barrier();
    GR_COMPUTE(sA1, sB1);
    __builtin_amdgcn_s_barrier();
  }
#undef GR_STAGE
#undef GR_COMPUTE

  float* outF = outp + (size_t)z * bStrideOut;
  const float* res = resid + (size_t)z * bStrideOut;
  int trow = tid >> 3;
  int tcol = (tid & 7) * 4;
  int growBase = m0 + (trow >> 4) * 64 + (trow & 15);
#pragma unroll
  for (int mi = 0; mi < 4; ++mi) {
    __syncthreads();
#pragma unroll
    for (int ni = 0; ni < 4; ++ni)
#pragma unroll
      for (int reg = 0; reg < 4; ++reg)
        tbuf[(wm * 16 + quad * 4 + reg) * 132 + wn * 64 + ni * 16 + lane15] = acc[mi][ni][reg];
    __syncthreads();
    int gr = growBase + mi * 16;
    float sh = shift3[gr];
    const float* rp = res + (size_t)gr * N + n0 + tcol;
    float* op = outF + (size_t)gr * N + n0 + tcol;
    const float* lp = &tbuf[trow * 132 + tcol];
#pragma unroll
    for (int j = 0; j < 4; ++j) {
      float4 rv = *(const float4*)(rp + j * 32);
      float4 lv = *(const float4*)(lp + j * 32);
      float4 ov;
      ov.x = fmaxf(lv.x + sh + rv.x, 0.f);
      ov.y = fmaxf(lv.y + sh + rv.y, 0.f);
      ov.z = fmaxf(lv.z + sh + rv.z, 0.f);
      ov.w = fmaxf(lv.w + sh + rv.w, 0.f);
      *(float4*)(op + j * 32) = ov;
    }
  }
}

// ---------------- offset conv as MFMA GEMM over padded act1P, depth-2 prefetch ----------------
// 1 block/CU regime: depth-2 pipeline (4 buffer sets, issue s+2 while computing s).
// Per stage = 3 DMAs; steady-state vmcnt(6) = stages s+1,s+2 in flight; tail 6/6/3/0.
__global__ __launch_bounds__(256) void off_gemm(const unsigned short* __restrict__ actP,
                                                const unsigned short* __restrict__ wob,
                                                const float* __restrict__ boff,
                                                float* __restrict__ offsP) {
  __shared__ __align__(16) unsigned short sA0[4096];
  __shared__ __align__(16) unsigned short sA1[4096];
  __shared__ __align__(16) unsigned short sA2[4096];
  __shared__ __align__(16) unsigned short sA3[4096];
  __shared__ __align__(16) unsigned short sB0[2048];
  __shared__ __align__(16) unsigned short sB1[2048];
  __shared__ __align__(16) unsigned short sB2[2048];
  __shared__ __align__(16) unsigned short sB3[2048];
  int tid = threadIdx.x, lane = tid & 63, wv = tid >> 6;
  int m0 = blockIdx.x * 64;
  int lane15 = lane & 15, quad8 = (lane >> 4) * 8;
  int rowA = tid >> 3;
  int kc = (tid & 7) * 8;

  const unsigned short* baseA[2];
#pragma unroll
  for (int r = 0; r < 2; ++r) {
    int row = m0 + r * 32 + rowA;
    int b = row >> 12, p = row & 4095;
    baseA[r] = actP + (((size_t)(b * 68) + (p >> 6) + 2) * 68 + (p & 63) + 2) * 256 + kc;
  }
  const unsigned short* baseB = wob + (size_t)rowA * 2304 + kc;

  f32x4 acc[2] = {};

#define OG_STAGE(dA, dB, S)                                                               \
  {                                                                                       \
    int s_ = (S); int kk_ = s_ >> 2; int c0_ = (s_ & 3) * 64;                             \
    long shift_ = (long)(((kk_ / 3) * 2 - 2) * 68 + ((kk_ % 3) * 2 - 2));                 \
    _Pragma("unroll") for (int r = 0; r < 2; ++r) {                                       \
      const unsigned short* gp = baseA[r] + shift_ * 256 + c0_;                           \
      __builtin_amdgcn_global_load_lds((const __attribute__((address_space(1))) void*)gp, \
          (__attribute__((address_space(3))) void*)&(dA)[r * 2048 + wv * 512], 16, 0, 0); \
    }                                                                                     \
    {                                                                                     \
      const unsigned short* gp = baseB + kk_ * 256 + c0_;                                 \
      __builtin_amdgcn_global_load_lds((const __attribute__((address_space(1))) void*)gp, \
          (__attribute__((address_space(3))) void*)&(dB)[wv * 512], 16, 0, 0);            \
    }                                                                                     \
  }

#define OG_COMPUTE(dA, dB)                                                                \
  {                                                                                       \
    bf16x8 afr[2], bfr[2][2];                                                             \
    _Pragma("unroll") for (int kq = 0; kq < 2; ++kq) {                                    \
      afr[kq] = *(const bf16x8*)&(dA)[(wv * 16 + lane15) * 64 + kq * 32 + quad8];         \
      _Pragma("unroll") for (int ni = 0; ni < 2; ++ni)                                    \
        bfr[kq][ni] = *(const bf16x8*)&(dB)[(ni * 16 + lane15) * 64 + kq * 32 + quad8];   \
    }                                                                                     \
    _Pragma("unroll") for (int kq = 0; kq < 2; ++kq)                                      \
      _Pragma("unroll") for (int ni = 0; ni < 2; ++ni)                                    \
        acc[ni] = __builtin_amdgcn_mfma_f32_16x16x32_bf16(afr[kq], bfr[kq][ni], acc[ni], 0, 0, 0); \
  }

#define OG_STEP6(AC, BC, SN, AN, BN_)                                                     \
  {                                                                                       \
    OG_STAGE(AN, BN_, SN);                                                                \
    asm volatile("s_waitcnt vmcnt(6)" ::: "memory");                                      \
    __builtin_amdgcn_s_barrier();                                                         \
    OG_COMPUTE(AC, BC);                                                                   \
    __builtin_amdgcn_s_barrier();                                                         \
  }

  OG_STAGE(sA0, sB0, 0);
  OG_STAGE(sA1, sB1, 1);
  for (int s4 = 0; s4 < 32; s4 += 4) {
    OG_STEP6(sA0, sB0, s4 + 2, sA2, sB2);
    OG_STEP6(sA1, sB1, s4 + 3, sA3, sB3);
    OG_STEP6(sA2, sB2, s4 + 4, sA0, sB0);
    OG_STEP6(sA3, sB3, s4 + 5, sA1, sB1);
  }
  OG_STEP6(sA0, sB0, 34, sA2, sB2);
  OG_STEP6(sA1, sB1, 35, sA3, sB3);
  asm volatile("s_waitcnt vmcnt(3)" ::: "memory");
  __builtin_amdgcn_s_barrier();
  OG_COMPUTE(sA2, sB2);
  __builtin_amdgcn_s_barrier();
  asm volatile("s_waitcnt vmcnt(0)" ::: "memory");
  __builtin_amdgcn_s_barrier();
  OG_COMPUTE(sA3, sB3);
#undef OG_STAGE
#undef OG_COMPUTE
#undef OG_STEP6

#pragma unroll
  for (int ni = 0; ni < 2; ++ni) {
    int o = ni * 16 + lane15;
    if (o < 18) {
      float bo = boff[o];
#pragma unroll
      for (int reg = 0; reg < 4; ++reg) {
        int row = m0 + wv * 16 + (lane >> 4) * 4 + reg;
        offsP[(size_t)row * 18 + o] = acc[ni][reg] + bo;
      }
    }
  }
}

// ---------------- bilinear im2col, vectorized: 32 lanes x 8ch per pixel ----------------
__global__ __launch_bounds__(256) void deform_sample(const unsigned short* __restrict__ act1T,
                                                     const float* __restrict__ offsP,
                                                     unsigned short* __restrict__ S) {
  int g = threadIdx.x >> 5, t = threadIdx.x & 31;
  int idx = blockIdx.x * 8 + g;
  int b = idx >> 12, p = idx & 4095;
  int h = p >> 6, w = p & 63;
  const unsigned short* actb = act1T + (size_t)b * 4096 * 256 + t * 8;
  unsigned short* Sp = S + (size_t)idx * 2304 + t * 8;
  float ov = (t < 18) ? offsP[(size_t)idx * 18 + t] : 0.f;
#pragma unroll
  for (int kk = 0; kk < 9; ++kk) {
    float offy = __shfl(ov, 2 * kk, 32);
    float offx = __shfl(ov, 2 * kk + 1, 32);
    float py = (float)(h + (kk / 3) * 2 - 2) + offy;
    float px = (float)(w + (kk % 3) * 2 - 2) + offx;
    float fy = floorf(py), fx = floorf(px);
    int y0 = (int)fy, x0 = (int)fx;
    float wy = py - fy, wx = px - fx;
    bool yv0 = (y0 >= 0 && y0 < 64), yv1 = (y0 >= -1 && y0 < 63);
    bool xv0 = (x0 >= 0 && x0 < 64), xv1 = (x0 >= -1 && x0 < 63);
    const unsigned short* cb = actb + (y0 * 64 + x0) * 256;
    uint4 q00{0,0,0,0}, q01{0,0,0,0}, q10{0,0,0,0}, q11{0,0,0,0};
    if (yv0 && xv0) q00 = *(const uint4*)(cb);
    if (yv0 && xv1) q01 = *(const uint4*)(cb + 256);
    if (yv1 && xv0) q10 = *(const uint4*)(cb + 64 * 256);
    if (yv1 && xv1) q11 = *(const uint4*)(cb + 64 * 256 + 256);
    float w00 = (1.f - wy) * (1.f - wx), w01 = (1.f - wy) * wx;
    float w10 = wy * (1.f - wx), w11 = wy * wx;
    unsigned u00[4] = {q00.x, q00.y, q00.z, q00.w};
    unsigned u01[4] = {q01.x, q01.y, q01.z, q01.w};
    unsigned u10[4] = {q10.x, q10.y, q10.z, q10.w};
    unsigned u11[4] = {q11.x, q11.y, q11.z, q11.w};
    unsigned out[4];
#pragma unroll
    for (int j = 0; j < 4; ++j) {
      float lo = bf2f((unsigned short)(u00[j] & 0xffffu)) * w00 +
                 bf2f((unsigned short)(u01[j] & 0xffffu)) * w01 +
                 bf2f((unsigned short)(u10[j] & 0xffffu)) * w10 +
                 bf2f((unsigned short)(u11[j] & 0xffffu)) * w11;
      float hi = bf2f((unsigned short)(u00[j] >> 16)) * w00 +
                 bf2f((unsigned short)(u01[j] >> 16)) * w01 +
                 bf2f((unsigned short)(u10[j] >> 16)) * w10 +
                 bf2f((unsigned short)(u11[j] >> 16)) * w11;
      out[j] = (unsigned)f2bf(lo) | ((unsigned)f2bf(hi) << 16);
    }
    *(uint4*)(Sp + kk * 256) = uint4{out[0], out[1], out[2], out[3]};
  }
}

extern "C" void kernel_launch(void* const* d_in, const int* in_sizes, int n_in,
                              void* d_out, int out_size, void* d_ws, size_t ws_size,
                              hipStream_t stream) {
  const float* x      = (const float*)d_in[0];
  const float* w1     = (const float*)d_in[1];
  const float* gamma1 = (const float*)d_in[2];
  const float* beta1  = (const float*)d_in[3];
  const float* mean1  = (const float*)d_in[4];
  const float* var1   = (const float*)d_in[5];
  const float* woff   = (const float*)d_in[6];
  const float* boff   = (const float*)d_in[7];
  const float* w2     = (const float*)d_in[8];
  const float* bconv2 = (const float*)d_in[9];
  const float* gamma2 = (const float*)d_in[10];
  const float* beta2  = (const float*)d_in[11];
  const float* mean2  = (const float*)d_in[12];
  const float* var2   = (const float*)d_in[13];
  const float* w3     = (const float*)d_in[14];
  const float* gamma3 = (const float*)d_in[15];
  const float* beta3  = (const float*)d_in[16];
  const float* mean3  = (const float*)d_in[17];
  const float* var3   = (const float*)d_in[18];

  char* ws = (char*)d_ws;
  unsigned short* act1T = (unsigned short*)(ws + 33554432);      //  8,388,608
  unsigned short* act2T = (unsigned short*)(ws + 41943040);      //  8,388,608
  unsigned short* S     = (unsigned short*)(ws + 50331648);      // 75,497,472 (ends 125,829,120)
  float*          offs  = (float*)(ws + 125829120);              //  1,179,648
  unsigned short* w1b   = (unsigned short*)(ws + 127008768);     //    524,288
  unsigned short* w2r   = (unsigned short*)(ws + 127533056);     //  1,179,648
  unsigned short* w3b   = (unsigned short*)(ws + 128712704);     //    524,288
  float*          bnS1  = (float*)(ws + 129236992);              //      1,024
  float*          bnH1  = (float*)(ws + 129238016);              //      1,024
  float*          bnS2  = (float*)(ws + 129239040);              //      1,024
  float*          bnH2  = (float*)(ws + 129240064);              //      1,024
  float*          shift3= (float*)(ws + 129241088);              //      4,096
  // aliased (non-overlapping lifetimes):
  unsigned short* act1P = S;                                  // 9.47 MB at S base; dead before S written
  unsigned short* part1 = (unsigned short*)(ws + 62914560);   // 2x8 MB bf16, in S region after act1P
  unsigned short* part2 = (unsigned short*)ws;                // 2x8 MB bf16 at ws base
  unsigned short* wob   = act2T;                              // 147 KB; dead before epi_bn2 writes act2T

  prep_all<<<4909, 256, 0, stream>>>(w1, w2, woff, w3,
                                     gamma1, beta1, mean1, var1,
                                     gamma2, beta2, mean2, var2, bconv2,
                                     gamma3, beta3, mean3, var3,
                                     w1b, w2r, (uint4*)act1P, wob, w3b, shift3,
                                     bnS1, bnH1, bnS2, bnH2);

  // GEMM1 (K=1024) with fused x-transpose, split x2 -> bf16 partials -> BN1+ReLU epilogue
  gemm1_x<<<dim3(2, 128, 2), 256, 0, stream>>>(x, w1b, part1, 512);
  epi_bn<2, 1><<<2048, 256, 0, stream>>>(part1, bnS1, bnH1, act1T, act1P);

  off_gemm<<<256, 256, 0, stream>>>(act1P, wob, boff, offs);
  deform_sample<<<dim3(2048), 256, 0, stream>>>(act1T, offs, S);

  // GEMM2 (K=2304) split x2, BK=64 swizzled superstep -> bf16 partials -> bias+BN2+ReLU epilogue
  gemm_split<<<dim3(2, 128, 2), 256, 0, stream>>>(S, w2r, part2, 16384, 256, 2304, 1152);
  epi_bn<2, 0><<<2048, 256, 0, stream>>>(part2, bnS2, bnH2, act2T, nullptr);

  // GEMM3: out = relu(w3s @ act2T^T + shift3 + x)
  gemm_res<<<dim3(32, 8, 4), 256, 0, stream>>>(w3b, act2T, (float*)d_out, shift3, x,
                                               1024, 4096, 256, 4096L * 256, 4194304L);
}

// Round 14
// 261.593 us; speedup vs baseline: 1.0417x; 1.0349x over previous
//
#include <hip/hip_runtime.h>

#define EPS_BN 1e-5f

typedef __bf16 bf16x8 __attribute__((ext_vector_type(8)));
typedef float f32x4 __attribute__((ext_vector_type(4)));

__device__ __forceinline__ unsigned short f2bf(float f) {
  union { float f; unsigned u; } v; v.f = f;
  unsigned r = v.u + 0x7fffu + ((v.u >> 16) & 1u);
  return (unsigned short)(r >> 16);
}
__device__ __forceinline__ float bf2f(unsigned short h) {
  union { unsigned u; float f; } v; v.u = ((unsigned)h) << 16;
  return v.f;
}

// ---------------- fused prep (act1P: pad-ring zeroing only; interior written by epi_bn1) ----------------
__global__ __launch_bounds__(256) void prep_all(
    const float* __restrict__ w1, const float* __restrict__ w2, const float* __restrict__ woff,
    const float* __restrict__ w3,
    const float* g1, const float* b1, const float* m1, const float* v1,
    const float* g2, const float* b2, const float* m2, const float* v2, const float* bconv2,
    const float* g3, const float* b3, const float* m3, const float* v3,
    unsigned short* __restrict__ w1b, unsigned short* __restrict__ w2r,
    uint4* __restrict__ act1Pz, unsigned short* __restrict__ wob,
    unsigned short* __restrict__ w3b, float* __restrict__ shift3,
    float* s1, float* h1, float* s2, float* h2) {
  int bid = blockIdx.x, tid = threadIdx.x;
  if (bid < 1024) {
    int i = bid * 256 + tid;
    w1b[i] = f2bf(w1[i]);
  } else if (bid < 3328) {
    int i = (bid - 1024) * 256 + tid;
    int o = i / 2304, r = i % 2304;
    int kk = r / 256, c = r % 256;
    w2r[i] = f2bf(w2[(size_t)o * 2304 + c * 9 + kk]);
  } else if (bid < 3592) {
    // zero the 2-wide pad ring of act1P: 4 batches x 528 ring cells x 32 uint4
    int i = (bid - 3328) * 256 + tid;        // 0..67583
    int cell = i >> 5, q = i & 31;
    int b = cell / 528, r = cell - b * 528;
    int row, col;
    if (r < 136) { row = r / 68; col = r % 68; }
    else if (r < 272) { int rr = r - 136; row = 66 + rr / 68; col = rr % 68; }
    else { int rr = r - 272; row = 2 + (rr >> 2); int c4 = rr & 3; col = (c4 < 2) ? c4 : c4 + 64; }
    act1Pz[(((size_t)(b * 68) + row) * 68 + col) * 32 + q] = uint4{0, 0, 0, 0};
  } else if (bid < 3880) {
    int i = (bid - 3592) * 256 + tid;
    int o = i / 2304, r = i % 2304;
    int kk = r / 256, c = r % 256;
    wob[i] = (o < 18) ? f2bf(woff[(size_t)o * 2304 + c * 9 + kk]) : (unsigned short)0;
  } else if (bid < 4904) {
    int i = (bid - 3880) * 256 + tid;
    int o = i >> 8;
    float sc = rsqrtf(v3[o] + EPS_BN) * g3[o];
    w3b[i] = f2bf(w3[i] * sc);
  } else if (bid < 4908) {
    int c = (bid - 4904) * 256 + tid;
    float sc = rsqrtf(v3[c] + EPS_BN) * g3[c];
    shift3[c] = b3[c] - m3[c] * sc;
  } else {
    int c = tid;
    float sc1 = rsqrtf(v1[c] + EPS_BN) * g1[c];
    s1[c] = sc1; h1[c] = b1[c] - m1[c] * sc1;
    float sc2 = rsqrtf(v2[c] + EPS_BN) * g2[c];
    s2[c] = sc2; h2[c] = b2[c] + (bconv2[c] - m2[c]) * sc2;
  }
}

// XCD-pairing swizzle for 512-block GEMM grids (2 n-blocks share an A-panel):
// hw lin id -> (xcd = lin&7, slot = lin>>3); pair P = xcd*32 + slot/2; x = slot&1.
// Pair members occupy hw ids 8 apart -> same XCD under round-robin -> A-panel L2-shared.
__device__ __forceinline__ void xcd_pair_map(int& xl, int& yl, int& zl) {
  int lin = blockIdx.x + 2 * (blockIdx.y + 128 * blockIdx.z);  // 0..511
  int xcd = lin & 7, slot = lin >> 3;
  int P = xcd * 32 + (slot >> 1);
  xl = slot & 1;
  yl = P & 127;
  zl = P >> 7;
}

// ---------------- GEMM1 with fused x-transpose: A staged from f32 x (c-major) ----------------
// Swizzled LDS (slot ^= row&3 within 64B rows) on A ds_write, B staging source, and reads.
__global__ __launch_bounds__(256) void gemm1_x(
    const float* __restrict__ x, const unsigned short* __restrict__ Bm,
    unsigned short* __restrict__ part, int KH) {
  __shared__ __align__(16) char blob[16896];              // sA0|sB0, tbuf aliases
  __shared__ __align__(16) unsigned short sA1[4096];
  __shared__ __align__(16) unsigned short sB1[4096];
  unsigned short* sA0 = (unsigned short*)blob;
  unsigned short* sB0 = (unsigned short*)(blob + 8192);
  float* tbuf = (float*)blob;                             // epilogue only
  int tid = threadIdx.x, lane = tid & 63, wv = tid >> 6;
  int bx, by, z;
  xcd_pair_map(bx, by, z);
  int m0 = by * 128, n0 = bx * 128;
  f32x4 acc[4][4] = {};
  // B staging mapping (pre-swizzled source col)
  int rowB = tid >> 2;
  int kcolBs = (((tid & 3) ^ (rowB & 3))) * 8;
  // A staging mapping: 2 threads/row, 16 ch each; swizzled write slots
  int px = tid & 127, chalf = tid >> 7;
  int s0w = (chalf * 2) ^ (px & 3), s1w = (chalf * 2 + 1) ^ (px & 3);
  int bb = m0 >> 12, p0 = m0 & 4095;
  const float* xa = x + (size_t)bb * 4194304 + (size_t)(chalf * 16) * 4096 + (p0 + px);
  int wm = wv & 1, wn = wv >> 1;
  int lane15 = lane & 15, quad = lane >> 4, l3 = lane & 3;

  float va[16];

#define G1_ISSUE_A(K0)                                                                    \
  {                                                                                       \
    const float* xp = xa + (size_t)(K0) * 4096;                                           \
    _Pragma("unroll") for (int j = 0; j < 16; ++j) va[j] = xp[(size_t)j * 4096];          \
  }

#define G1_ISSUE_B(DB, K0)                                                                \
  {                                                                                       \
    _Pragma("unroll") for (int r = 0; r < 2; ++r) {                                       \
      const unsigned short* gp = Bm + (size_t)(n0 + r * 64 + rowB) * 1024 + (K0) + kcolBs;\
      __builtin_amdgcn_global_load_lds((const __attribute__((address_space(1))) void*)gp, \
          (__attribute__((address_space(3))) void*)&(DB)[r * 2048 + wv * 512], 16, 0, 0); \
    }                                                                                     \
  }

#define G1_CVT_WRITE(DA)                                                                  \
  {                                                                                       \
    unsigned o8[8];                                                                       \
    _Pragma("unroll") for (int j = 0; j < 8; ++j)                                         \
      o8[j] = (unsigned)f2bf(va[2 * j]) | ((unsigned)f2bf(va[2 * j + 1]) << 16);          \
    *(uint4*)((DA) + px * 32 + s0w * 8) = uint4{o8[0], o8[1], o8[2], o8[3]};              \
    *(uint4*)((DA) + px * 32 + s1w * 8) = uint4{o8[4], o8[5], o8[6], o8[7]};              \
  }

#define G1_COMPUTE(DA, DB)                                                                \
  {                                                                                       \
    bf16x8 afr[4], bfr[4];                                                                \
    _Pragma("unroll") for (int mi = 0; mi < 4; ++mi)                                      \
      afr[mi] = *(const bf16x8*)&(DA)[(wm * 64 + mi * 16 + lane15) * 32 + (quad ^ l3) * 8]; \
    _Pragma("unroll") for (int ni = 0; ni < 4; ++ni)                                      \
      bfr[ni] = *(const bf16x8*)&(DB)[(wn * 64 + ni * 16 + lane15) * 32 + (quad ^ l3) * 8]; \
    _Pragma("unroll") for (int mi = 0; mi < 4; ++mi)                                      \
      _Pragma("unroll") for (int ni = 0; ni < 4; ++ni)                                    \
        acc[mi][ni] =                                                                     \
            __builtin_amdgcn_mfma_f32_16x16x32_bf16(afr[mi], bfr[ni], acc[mi][ni], 0, 0, 0); \
  }

#define G1_BODY(K0, AC, BC, AN, BN_)                                                      \
  {                                                                                       \
    G1_ISSUE_A(K0);                                                                       \
    G1_ISSUE_B(BN_, K0);                                                                  \
    asm volatile("s_waitcnt vmcnt(18)" ::: "memory");                                     \
    asm volatile("s_waitcnt lgkmcnt(0)" ::: "memory");                                    \
    __builtin_amdgcn_s_barrier();                                                         \
    G1_COMPUTE(AC, BC);                                                                   \
    asm volatile("s_waitcnt vmcnt(2)" ::: "memory");                                      \
    G1_CVT_WRITE(AN);                                                                     \
    __builtin_amdgcn_s_barrier();                                                         \
  }

  int kbase = z * KH;
  int nst = KH >> 5;  // 16: even
  G1_ISSUE_A(kbase);
  G1_ISSUE_B(sB0, kbase);
  asm volatile("s_waitcnt vmcnt(2)" ::: "memory");
  G1_CVT_WRITE(sA0);
  for (int t = 0; t + 2 < nst; t += 2) {
    G1_BODY(kbase + (t + 1) * 32, sA0, sB0, sA1, sB1);
    G1_BODY(kbase + (t + 2) * 32, sA1, sB1, sA0, sB0);
  }
  G1_BODY(kbase + (nst - 1) * 32, sA0, sB0, sA1, sB1);
  asm volatile("s_waitcnt vmcnt(0)" ::: "memory");
  asm volatile("s_waitcnt lgkmcnt(0)" ::: "memory");
  __builtin_amdgcn_s_barrier();
  G1_COMPUTE(sA1, sB1);
#undef G1_ISSUE_A
#undef G1_ISSUE_B
#undef G1_CVT_WRITE
#undef G1_COMPUTE
#undef G1_BODY

  // vectorized epilogue -> z-partial
  unsigned short* outH = part + (size_t)z * 16384 * 256;
  int trow = tid >> 3;
  int tcol16 = (tid & 7) * 16;
  int growBase = m0 + (trow >> 4) * 64 + (trow & 15);
#pragma unroll
  for (int mi = 0; mi < 4; ++mi) {
    __syncthreads();
#pragma unroll
    for (int ni = 0; ni < 4; ++ni)
#pragma unroll
      for (int reg = 0; reg < 4; ++reg)
        tbuf[(wm * 16 + quad * 4 + reg) * 132 + wn * 64 + ni * 16 + lane15] = acc[mi][ni][reg];
    __syncthreads();
    int gr = growBase + mi * 16;
    const float* lp = &tbuf[trow * 132 + tcol16];
    unsigned o[8];
#pragma unroll
    for (int j = 0; j < 8; ++j)
      o[j] = (unsigned)f2bf(lp[2 * j]) | ((unsigned)f2bf(lp[2 * j + 1]) << 16);
    unsigned short* op = outH + (size_t)gr * 256 + n0 + tcol16;
    *(uint4*)(op) = uint4{o[0], o[1], o[2], o[3]};
    *(uint4*)(op + 8) = uint4{o[4], o[5], o[6], o[7]};
  }
}

// ---------------- GEMM2: BK=64 superstep, swizzled LDS (slot ^= row&7), vmcnt(8) ----------------
__global__ __launch_bounds__(256) void gemm_split(
    const unsigned short* __restrict__ A, const unsigned short* __restrict__ Bm,
    unsigned short* __restrict__ part, int M, int N, int K, int KH) {
  __shared__ __align__(16) char blob[32768];              // sA0|sB0 (16K each), tbuf aliases
  __shared__ __align__(16) unsigned short sA1[8192];
  __shared__ __align__(16) unsigned short sB1[8192];
  unsigned short* sA0 = (unsigned short*)blob;
  unsigned short* sB0 = (unsigned short*)(blob + 16384);
  float* tbuf = (float*)blob;                             // epilogue only
  int tid = threadIdx.x, lane = tid & 63, wv = tid >> 6;
  int bx, by, z;
  xcd_pair_map(bx, by, z);
  int m0 = by * 128, n0 = bx * 128;
  f32x4 acc[4][4] = {};
  int rowS = tid >> 3;               // 0..31 staging row within call
  int colS = (((tid & 7) ^ (rowS & 7))) * 8;  // pre-swizzled source col (elements)
  int wm = wv & 1, wn = wv >> 1;
  int lane15 = lane & 15, quad = lane >> 4, l7 = lane & 7;

#define GS_STAGE(dA, dB, K0)                                                              \
  {                                                                                       \
    int k0_ = (K0);                                                                       \
    _Pragma("unroll") for (int r = 0; r < 4; ++r) {                                       \
      const unsigned short* gp = A + (size_t)(m0 + r * 32 + rowS) * K + k0_ + colS;       \
      __builtin_amdgcn_global_load_lds((const __attribute__((address_space(1))) void*)gp, \
          (__attribute__((address_space(3))) void*)&(dA)[r * 2048 + wv * 512], 16, 0, 0); \
    }                                                                                     \
    _Pragma("unroll") for (int r = 0; r < 4; ++r) {                                       \
      const unsigned short* gp = Bm + (size_t)(n0 + r * 32 + rowS) * K + k0_ + colS;      \
      __builtin_amdgcn_global_load_lds((const __attribute__((address_space(1))) void*)gp, \
          (__attribute__((address_space(3))) void*)&(dB)[r * 2048 + wv * 512], 16, 0, 0); \
    }                                                                                     \
  }

#define GS_COMPUTE(dA, dB)                                                                \
  {                                                                                       \
    _Pragma("unroll") for (int kq = 0; kq < 2; ++kq) {                                    \
      bf16x8 afr[4], bfr[4];                                                              \
      _Pragma("unroll") for (int mi = 0; mi < 4; ++mi)                                    \
        afr[mi] = *(const bf16x8*)&(dA)[(wm * 64 + mi * 16 + lane15) * 64 +               \
                                        ((kq * 4 + quad) ^ l7) * 8];                      \
      _Pragma("unroll") for (int ni = 0; ni < 4; ++ni)                                    \
        bfr[ni] = *(const bf16x8*)&(dB)[(wn * 64 + ni * 16 + lane15) * 64 +               \
                                        ((kq * 4 + quad) ^ l7) * 8];                      \
      _Pragma("unroll") for (int mi = 0; mi < 4; ++mi)                                    \
        _Pragma("unroll") for (int ni = 0; ni < 4; ++ni)                                  \
          acc[mi][ni] =                                                                   \
              __builtin_amdgcn_mfma_f32_16x16x32_bf16(afr[mi], bfr[ni], acc[mi][ni], 0, 0, 0); \
    }                                                                                     \
  }

  int kbase = z * KH;
  int nst = KH >> 6;  // 18 (GEMM2 z=2): even
  GS_STAGE(sA0, sB0, kbase);
  for (int t = 0; t < nst; t += 2) {
    GS_STAGE(sA1, sB1, kbase + (t + 1) * 64);
    asm volatile("s_waitcnt vmcnt(8)" ::: "memory");
    __builtin_amdgcn_s_barrier();
    GS_COMPUTE(sA0, sB0);
    __builtin_amdgcn_s_barrier();
    if (t + 2 < nst) {
      GS_STAGE(sA0, sB0, kbase + (t + 2) * 64);
      asm volatile("s_waitcnt vmcnt(8)" ::: "memory");
    } else {
      asm volatile("s_waitcnt vmcnt(0)" ::: "memory");
    }
    __builtin_amdgcn_s_barrier();
    GS_COMPUTE(sA1, sB1);
    __builtin_amdgcn_s_barrier();
  }
#undef GS_STAGE
#undef GS_COMPUTE

  // vectorized epilogue: LDS-transpose each 32-row chunk, pack 16ch/thread -> 2 uint4 stores
  unsigned short* outH = part + (size_t)z * M * N;
  int trow = tid >> 3;              // 0..31
  int tcol16 = (tid & 7) * 16;      // 0..112
  int growBase = m0 + (trow >> 4) * 64 + (trow & 15);
#pragma unroll
  for (int mi = 0; mi < 4; ++mi) {
    __syncthreads();
#pragma unroll
    for (int ni = 0; ni < 4; ++ni)
#pragma unroll
      for (int reg = 0; reg < 4; ++reg)
        tbuf[(wm * 16 + quad * 4 + reg) * 132 + wn * 64 + ni * 16 + lane15] = acc[mi][ni][reg];
    __syncthreads();
    int gr = growBase + mi * 16;
    const float* lp = &tbuf[trow * 132 + tcol16];
    unsigned o[8];
#pragma unroll
    for (int j = 0; j < 8; ++j)
      o[j] = (unsigned)f2bf(lp[2 * j]) | ((unsigned)f2bf(lp[2 * j + 1]) << 16);
    unsigned short* op = outH + (size_t)gr * 256 + n0 + tcol16;
    *(uint4*)(op) = uint4{o[0], o[1], o[2], o[3]};
    *(uint4*)(op + 8) = uint4{o[4], o[5], o[6], o[7]};
  }
}

// ---------------- epilogue: sum NS bf16 partials, folded BN + ReLU -> bf16 (+opt padded copy) ----------------
template <int NS, int PAD>
__global__ __launch_bounds__(256) void epi_bn(const unsigned short* __restrict__ part,
                                              const float* __restrict__ scale,
                                              const float* __restrict__ shift,
                                              unsigned short* __restrict__ outT,
                                              unsigned short* __restrict__ outP) {
  int gid = blockIdx.x * 256 + threadIdx.x;   // 16384*32
  int row = gid >> 5, c0 = (gid & 31) * 8;
  float v[8] = {};
#pragma unroll
  for (int s = 0; s < NS; ++s) {
    uint4 q = *(const uint4*)(part + (size_t)s * 16384 * 256 + (size_t)row * 256 + c0);
    unsigned u[4] = {q.x, q.y, q.z, q.w};
#pragma unroll
    for (int j = 0; j < 4; ++j) {
      v[2 * j]     += bf2f((unsigned short)(u[j] & 0xffffu));
      v[2 * j + 1] += bf2f((unsigned short)(u[j] >> 16));
    }
  }
  float sc[8], sh[8];
  *(float4*)&sc[0] = *(const float4*)(scale + c0); *(float4*)&sc[4] = *(const float4*)(scale + c0 + 4);
  *(float4*)&sh[0] = *(const float4*)(shift + c0); *(float4*)&sh[4] = *(const float4*)(shift + c0 + 4);
  unsigned o[4];
#pragma unroll
  for (int j = 0; j < 4; ++j) {
    float lo = fmaxf(v[2 * j] * sc[2 * j] + sh[2 * j], 0.f);
    float hi = fmaxf(v[2 * j + 1] * sc[2 * j + 1] + sh[2 * j + 1], 0.f);
    o[j] = (unsigned)f2bf(lo) | ((unsigned)f2bf(hi) << 16);
  }
  uint4 pk{o[0], o[1], o[2], o[3]};
  *(uint4*)(outT + (size_t)row * 256 + c0) = pk;
  if constexpr (PAD) {
    int bb = row >> 12, p = row & 4095;
    *(uint4*)(outP + (((size_t)(bb * 68) + (p >> 6) + 2) * 68 + (p & 63) + 2) * 256 + c0) = pk;
  }
}

// ---------------- final GEMM (1x1 conv #3), BN3 pre-folded, T4 pipeline + swizzle ----------------
__global__ __launch_bounds__(256) void gemm_res(
    const unsigned short* __restrict__ A, const unsigned short* __restrict__ Bm,
    float* __restrict__ outp, const float* __restrict__ shift3,
    const float* __restrict__ resid, int M, int N, int K, long bStrideB, long bStrideOut) {
  __shared__ __align__(16) char blob[16896];
  __shared__ __align__(16) unsigned short sA1[4096];
  __shared__ __align__(16) unsigned short sB1[4096];
  unsigned short* sA0 = (unsigned short*)blob;
  unsigned short* sB0 = (unsigned short*)(blob + 8192);
  float* tbuf = (float*)blob;
  int tid = threadIdx.x, lane = tid & 63, wv = tid >> 6;
  int z = blockIdx.z;
  const unsigned short* Bz = Bm + (size_t)z * bStrideB;
  int m0 = blockIdx.y * 128, n0 = blockIdx.x * 128;
  f32x4 acc[4][4] = {};
  int rowA = tid >> 2;
  int kcolS = (((tid & 3) ^ (rowA & 3))) * 8;   // pre-swizzled source col
  int wm = wv & 1, wn = wv >> 1;
  int lane15 = lane & 15, quad = lane >> 4, l3 = lane & 3;

#define GR_STAGE(dA, dB, K0)                                                              \
  {                                                                                       \
    int k0_ = (K0);                                                                       \
    _Pragma("unroll") for (int r = 0; r < 2; ++r) {                                       \
      const unsigned short* gp = A + (size_t)(m0 + r * 64 + rowA) * K + k0_ + kcolS;      \
      __builtin_amdgcn_global_load_lds((const __attribute__((address_space(1))) void*)gp, \
          (__attribute__((address_space(3))) void*)&(dA)[r * 2048 + wv * 512], 16, 0, 0); \
    }                                                                                     \
    _Pragma("unroll") for (int r = 0; r < 2; ++r) {                                       \
      const unsigned short* gp = Bz + (size_t)(n0 + r * 64 + rowA) * K + k0_ + kcolS;     \
      __builtin_amdgcn_global_load_lds((const __attribute__((address_space(1))) void*)gp, \
          (__attribute__((address_space(3))) void*)&(dB)[r * 2048 + wv * 512], 16, 0, 0); \
    }                                                                                     \
  }

#define GR_COMPUTE(dA, dB)                                                                \
  {                                                                                       \
    bf16x8 afr[4], bfr[4];                                                                \
    _Pragma("unroll") for (int mi = 0; mi < 4; ++mi)                                      \
      afr[mi] = *(const bf16x8*)&(dA)[(wm * 64 + mi * 16 + lane15) * 32 + (quad ^ l3) * 8]; \
    _Pragma("unroll") for (int ni = 0; ni < 4; ++ni)                                      \
      bfr[ni] = *(const bf16x8*)&(dB)[(wn * 64 + ni * 16 + lane15) * 32 + (quad ^ l3) * 8]; \
    _Pragma("unroll") for (int mi = 0; mi < 4; ++mi)                                      \
      _Pragma("unroll") for (int ni = 0; ni < 4; ++ni)                                    \
        acc[mi][ni] =                                                                     \
            __builtin_amdgcn_mfma_f32_16x16x32_bf16(afr[mi], bfr[ni], acc[mi][ni], 0, 0, 0); \
  }

  int nst = K >> 5;  // 8: even
  GR_STAGE(sA0, sB0, 0);
  for (int t = 0; t < nst; t += 2) {
    GR_STAGE(sA1, sB1, (t + 1) * 32);
    asm volatile("s_waitcnt vmcnt(4)" ::: "memory");
    __builtin_amdgcn_s_barrier();
    GR_COMPUTE(sA0, sB0);
    __builtin_amdgcn_s_barrier();
    if (t + 2 < nst) {
      GR_STAGE(sA0, sB0, (t + 2) * 32);
      asm volatile("s_waitcnt vmcnt(4)" ::: "memory");
    } else {
      asm volatile("s_waitcnt vmcnt(0)" ::: "memory");
    }
    __builtin_amdgcn_s_barrier();
    GR_COMPUTE(sA1, sB1);
    __builtin_amdgcn_s_barrier();
  }
#undef GR_STAGE
#undef GR_COMPUTE

  float* outF = outp + (size_t)z * bStrideOut;
  const float* res = resid + (size_t)z * bStrideOut;
  int trow = tid >> 3;
  int tcol = (tid & 7) * 4;
  int growBase = m0 + (trow >> 4) * 64 + (trow & 15);
#pragma unroll
  for (int mi = 0; mi < 4; ++mi) {
    __syncthreads();
#pragma unroll
    for (int ni = 0; ni < 4; ++ni)
#pragma unroll
      for (int reg = 0; reg < 4; ++reg)
        tbuf[(wm * 16 + quad * 4 + reg) * 132 + wn * 64 + ni * 16 + lane15] = acc[mi][ni][reg];
    __syncthreads();
    int gr = growBase + mi * 16;
    float sh = shift3[gr];
    const float* rp = res + (size_t)gr * N + n0 + tcol;
    float* op = outF + (size_t)gr * N + n0 + tcol;
    const float* lp = &tbuf[trow * 132 + tcol];
#pragma unroll
    for (int j = 0; j < 4; ++j) {
      float4 rv = *(const float4*)(rp + j * 32);
      float4 lv = *(const float4*)(lp + j * 32);
      float4 ov;
      ov.x = fmaxf(lv.x + sh + rv.x, 0.f);
      ov.y = fmaxf(lv.y + sh + rv.y, 0.f);
      ov.z = fmaxf(lv.z + sh + rv.z, 0.f);
      ov.w = fmaxf(lv.w + sh + rv.w, 0.f);
      *(float4*)(op + j * 32) = ov;
    }
  }
}

// ---------------- offset conv as MFMA GEMM over padded act1P, depth-2 prefetch ----------------
// 1 block/CU regime: depth-2 pipeline (4 buffer sets, issue s+2 while computing s).
// Per stage = 3 DMAs; steady-state vmcnt(6) = stages s+1,s+2 in flight; tail 6/6/3/0.
__global__ __launch_bounds__(256) void off_gemm(const unsigned short* __restrict__ actP,
                                                const unsigned short* __restrict__ wob,
                                                const float* __restrict__ boff,
                                                float* __restrict__ offsP) {
  __shared__ __align__(16) unsigned short sA0[4096];
  __shared__ __align__(16) unsigned short sA1[4096];
  __shared__ __align__(16) unsigned short sA2[4096];
  __shared__ __align__(16) unsigned short sA3[4096];
  __shared__ __align__(16) unsigned short sB0[2048];
  __shared__ __align__(16) unsigned short sB1[2048];
  __shared__ __align__(16) unsigned short sB2[2048];
  __shared__ __align__(16) unsigned short sB3[2048];
  int tid = threadIdx.x, lane = tid & 63, wv = tid >> 6;
  int m0 = blockIdx.x * 64;
  int lane15 = lane & 15, quad8 = (lane >> 4) * 8;
  int rowA = tid >> 3;
  int kc = (tid & 7) * 8;

  const unsigned short* baseA[2];
#pragma unroll
  for (int r = 0; r < 2; ++r) {
    int row = m0 + r * 32 + rowA;
    int b = row >> 12, p = row & 4095;
    baseA[r] = actP + (((size_t)(b * 68) + (p >> 6) + 2) * 68 + (p & 63) + 2) * 256 + kc;
  }
  const unsigned short* baseB = wob + (size_t)rowA * 2304 + kc;

  f32x4 acc[2] = {};

#define OG_STAGE(dA, dB, S)                                                               \
  {                                                                                       \
    int s_ = (S); int kk_ = s_ >> 2; int c0_ = (s_ & 3) * 64;                             \
    long shift_ = (long)(((kk_ / 3) * 2 - 2) * 68 + ((kk_ % 3) * 2 - 2));                 \
    _Pragma("unroll") for (int r = 0; r < 2; ++r) {                                       \
      const unsigned short* gp = baseA[r] + shift_ * 256 + c0_;                           \
      __builtin_amdgcn_global_load_lds((const __attribute__((address_space(1))) void*)gp, \
          (__attribute__((address_space(3))) void*)&(dA)[r * 2048 + wv * 512], 16, 0, 0); \
    }                                                                                     \
    {                                                                                     \
      const unsigned short* gp = baseB + kk_ * 256 + c0_;                                 \
      __builtin_amdgcn_global_load_lds((const __attribute__((address_space(1))) void*)gp, \
          (__attribute__((address_space(3))) void*)&(dB)[wv * 512], 16, 0, 0);            \
    }                                                                                     \
  }

#define OG_COMPUTE(dA, dB)                                                                \
  {                                                                                       \
    bf16x8 afr[2], bfr[2][2];                                                             \
    _Pragma("unroll") for (int kq = 0; kq < 2; ++kq) {                                    \
      afr[kq] = *(const bf16x8*)&(dA)[(wv * 16 + lane15) * 64 + kq * 32 + quad8];         \
      _Pragma("unroll") for (int ni = 0; ni < 2; ++ni)                                    \
        bfr[kq][ni] = *(const bf16x8*)&(dB)[(ni * 16 + lane15) * 64 + kq * 32 + quad8];   \
    }                                                                                     \
    _Pragma("unroll") for (int kq = 0; kq < 2; ++kq)                                      \
      _Pragma("unroll") for (int ni = 0; ni < 2; ++ni)                                    \
        acc[ni] = __builtin_amdgcn_mfma_f32_16x16x32_bf16(afr[kq], bfr[kq][ni], acc[ni], 0, 0, 0); \
  }

#define OG_STEP6(AC, BC, SN, AN, BN_)                                                     \
  {                                                                                       \
    OG_STAGE(AN, BN_, SN);                                                                \
    asm volatile("s_waitcnt vmcnt(6)" ::: "memory");                                      \
    __builtin_amdgcn_s_barrier();                                                         \
    OG_COMPUTE(AC, BC);                                                                   \
    __builtin_amdgcn_s_barrier();                                                         \
  }

  OG_STAGE(sA0, sB0, 0);
  OG_STAGE(sA1, sB1, 1);
  for (int s4 = 0; s4 < 32; s4 += 4) {
    OG_STEP6(sA0, sB0, s4 + 2, sA2, sB2);
    OG_STEP6(sA1, sB1, s4 + 3, sA3, sB3);
    OG_STEP6(sA2, sB2, s4 + 4, sA0, sB0);
    OG_STEP6(sA3, sB3, s4 + 5, sA1, sB1);
  }
  OG_STEP6(sA0, sB0, 34, sA2, sB2);
  OG_STEP6(sA1, sB1, 35, sA3, sB3);
  asm volatile("s_waitcnt vmcnt(3)" ::: "memory");
  __builtin_amdgcn_s_barrier();
  OG_COMPUTE(sA2, sB2);
  __builtin_amdgcn_s_barrier();
  asm volatile("s_waitcnt vmcnt(0)" ::: "memory");
  __builtin_amdgcn_s_barrier();
  OG_COMPUTE(sA3, sB3);
#undef OG_STAGE
#undef OG_COMPUTE
#undef OG_STEP6

#pragma unroll
  for (int ni = 0; ni < 2; ++ni) {
    int o = ni * 16 + lane15;
    if (o < 18) {
      float bo = boff[o];
#pragma unroll
      for (int reg = 0; reg < 4; ++reg) {
        int row = m0 + wv * 16 + (lane >> 4) * 4 + reg;
        offsP[(size_t)row * 18 + o] = acc[ni][reg] + bo;
      }
    }
  }
}

// ---------------- bilinear im2col, vectorized: 32 lanes x 8ch per pixel ----------------
__global__ __launch_bounds__(256) void deform_sample(const unsigned short* __restrict__ act1T,
                                                     const float* __restrict__ offsP,
                                                     unsigned short* __restrict__ S) {
  int g = threadIdx.x >> 5, t = threadIdx.x & 31;
  int idx = blockIdx.x * 8 + g;
  int b = idx >> 12, p = idx & 4095;
  int h = p >> 6, w = p & 63;
  const unsigned short* actb = act1T + (size_t)b * 4096 * 256 + t * 8;
  unsigned short* Sp = S + (size_t)idx * 2304 + t * 8;
  float ov = (t < 18) ? offsP[(size_t)idx * 18 + t] : 0.f;
#pragma unroll
  for (int kk = 0; kk < 9; ++kk) {
    float offy = __shfl(ov, 2 * kk, 32);
    float offx = __shfl(ov, 2 * kk + 1, 32);
    float py = (float)(h + (kk / 3) * 2 - 2) + offy;
    float px = (float)(w + (kk % 3) * 2 - 2) + offx;
    float fy = floorf(py), fx = floorf(px);
    int y0 = (int)fy, x0 = (int)fx;
    float wy = py - fy, wx = px - fx;
    bool yv0 = (y0 >= 0 && y0 < 64), yv1 = (y0 >= -1 && y0 < 63);
    bool xv0 = (x0 >= 0 && x0 < 64), xv1 = (x0 >= -1 && x0 < 63);
    const unsigned short* cb = actb + (y0 * 64 + x0) * 256;
    uint4 q00{0,0,0,0}, q01{0,0,0,0}, q10{0,0,0,0}, q11{0,0,0,0};
    if (yv0 && xv0) q00 = *(const uint4*)(cb);
    if (yv0 && xv1) q01 = *(const uint4*)(cb + 256);
    if (yv1 && xv0) q10 = *(const uint4*)(cb + 64 * 256);
    if (yv1 && xv1) q11 = *(const uint4*)(cb + 64 * 256 + 256);
    float w00 = (1.f - wy) * (1.f - wx), w01 = (1.f - wy) * wx;
    float w10 = wy * (1.f - wx), w11 = wy * wx;
    unsigned u00[4] = {q00.x, q00.y, q00.z, q00.w};
    unsigned u01[4] = {q01.x, q01.y, q01.z, q01.w};
    unsigned u10[4] = {q10.x, q10.y, q10.z, q10.w};
    unsigned u11[4] = {q11.x, q11.y, q11.z, q11.w};
    unsigned out[4];
#pragma unroll
    for (int j = 0; j < 4; ++j) {
      float lo = bf2f((unsigned short)(u00[j] & 0xffffu)) * w00 +
                 bf2f((unsigned short)(u01[j] & 0xffffu)) * w01 +
                 bf2f((unsigned short)(u10[j] & 0xffffu)) * w10 +
                 bf2f((unsigned short)(u11[j] & 0xffffu)) * w11;
      float hi = bf2f((unsigned short)(u00[j] >> 16)) * w00 +
                 bf2f((unsigned short)(u01[j] >> 16)) * w01 +
                 bf2f((unsigned short)(u10[j] >> 16)) * w10 +
                 bf2f((unsigned short)(u11[j] >> 16)) * w11;
      out[j] = (unsigned)f2bf(lo) | ((unsigned)f2bf(hi) << 16);
    }
    *(uint4*)(Sp + kk * 256) = uint4{out[0], out[1], out[2], out[3]};
  }
}

extern "C" void kernel_launch(void* const* d_in, const int* in_sizes, int n_in,
                              void* d_out, int out_size, void* d_ws, size_t ws_size,
                              hipStream_t stream) {
  const float* x      = (const float*)d_in[0];
  const float* w1     = (const float*)d_in[1];
  const float* gamma1 = (const float*)d_in[2];
  const float* beta1  = (const float*)d_in[3];
  const float* mean1  = (const float*)d_in[4];
  const float* var1   = (const float*)d_in[5];
  const float* woff   = (const float*)d_in[6];
  const float* boff   = (const float*)d_in[7];
  const float* w2     = (const float*)d_in[8];
  const float* bconv2 = (const float*)d_in[9];
  const float* gamma2 = (const float*)d_in[10];
  const float* beta2  = (const float*)d_in[11];
  const float* mean2  = (const float*)d_in[12];
  const float* var2   = (const float*)d_in[13];
  const float* w3     = (const float*)d_in[14];
  const float* gamma3 = (const float*)d_in[15];
  const float* beta3  = (const float*)d_in[16];
  const float* mean3  = (const float*)d_in[17];
  const float* var3   = (const float*)d_in[18];

  char* ws = (char*)d_ws;
  unsigned short* act1T = (unsigned short*)(ws + 33554432);      //  8,388,608
  unsigned short* act2T = (unsigned short*)(ws + 41943040);      //  8,388,608
  unsigned short* S     = (unsigned short*)(ws + 50331648);      // 75,497,472 (ends 125,829,120)
  float*          offs  = (float*)(ws + 125829120);              //  1,179,648
  unsigned short* w1b   = (unsigned short*)(ws + 127008768);     //    524,288
  unsigned short* w2r   = (unsigned short*)(ws + 127533056);     //  1,179,648
  unsigned short* w3b   = (unsigned short*)(ws + 128712704);     //    524,288
  float*          bnS1  = (float*)(ws + 129236992);              //      1,024
  float*          bnH1  = (float*)(ws + 129238016);              //      1,024
  float*          bnS2  = (float*)(ws + 129239040);              //      1,024
  float*          bnH2  = (float*)(ws + 129240064);              //      1,024
  float*          shift3= (float*)(ws + 129241088);              //      4,096
  // aliased (non-overlapping lifetimes):
  unsigned short* act1P = S;                                  // 9.47 MB at S base; dead before S written
  unsigned short* part1 = (unsigned short*)(ws + 62914560);   // 2x8 MB bf16, in S region after act1P
  unsigned short* part2 = (unsigned short*)ws;                // 2x8 MB bf16 at ws base
  unsigned short* wob   = act2T;                              // 147 KB; dead before epi_bn2 writes act2T

  prep_all<<<4909, 256, 0, stream>>>(w1, w2, woff, w3,
                                     gamma1, beta1, mean1, var1,
                                     gamma2, beta2, mean2, var2, bconv2,
                                     gamma3, beta3, mean3, var3,
                                     w1b, w2r, (uint4*)act1P, wob, w3b, shift3,
                                     bnS1, bnH1, bnS2, bnH2);

  // GEMM1 (K=1024) with fused x-transpose, split x2 -> bf16 partials -> BN1+ReLU epilogue
  gemm1_x<<<dim3(2, 128, 2), 256, 0, stream>>>(x, w1b, part1, 512);
  epi_bn<2, 1><<<2048, 256, 0, stream>>>(part1, bnS1, bnH1, act1T, act1P);

  off_gemm<<<256, 256, 0, stream>>>(act1P, wob, boff, offs);
  deform_sample<<<dim3(2048), 256, 0, stream>>>(act1T, offs, S);

  // GEMM2 (K=2304) split x2, BK=64 swizzled superstep -> bf16 partials -> bias+BN2+ReLU epilogue
  gemm_split<<<dim3(2, 128, 2), 256, 0, stream>>>(S, w2r, part2, 16384, 256, 2304, 1152);
  epi_bn<2, 0><<<2048, 256, 0, stream>>>(part2, bnS2, bnH2, act2T, nullptr);

  // GEMM3: out = relu(w3s @ act2T^T + shift3 + x)
  gemm_res<<<dim3(32, 8, 4), 256, 0, stream>>>(w3b, act2T, (float*)d_out, shift3, x,
                                               1024, 4096, 256, 4096L * 256, 4194304L);
}